// Round 3
// baseline (3095.292 us; speedup 1.0000x reference)
//
#include <hip/hip_runtime.h>
#include <math.h>

#define B_ 8
#define N_ 4096
#define K_ 20
#define KS_ 24          // approx-select width; exact rescore trims to K_
#define BN_ (B_*N_)

typedef __attribute__((ext_vector_type(8))) short bf16x8;
typedef __attribute__((ext_vector_type(4))) float f32x4;

// ---------------------------------------------------------------- utilities
__global__ void zero_kernel(float* p, int n)
{
    for (int e = threadIdx.x; e < n; e += 256) p[e] = 0.f;
}

// mean/rstd from accumulated sum/sumsq.  layout: [sum(H), sumsq(H), mean(H), rstd(H)]
__global__ void finalize_kernel(float* st, int H, float invCount)
{
    int t = threadIdx.x;
    if (t < H) {
        float mean = st[t] * invCount;
        float var  = fmaxf(st[H + t] * invCount - mean * mean, 0.f);
        st[2*H + t] = mean;
        st[3*H + t] = 1.f / sqrtf(var + 1e-5f);
    }
}

// ---------------------------------------------------------------- kNN, C=4
__global__ __launch_bounds__(1024) void knn4_kernel(const float* __restrict__ x, int* __restrict__ idxout)
{
    __shared__ float4 xt[N_];
    const int b = blockIdx.y;
    const int t = threadIdx.x;
    const float4* xg = (const float4*)x + b*N_;
    for (int e = t; e < N_; e += 1024) xt[e] = xg[e];
    __syncthreads();
    const int w = t >> 6, L = t & 63;
    const int n = blockIdx.x*16 + w;
    const float4 q = xt[n];
    float d[64];
    #pragma unroll
    for (int s = 0; s < 64; ++s) {
        float4 v = xt[(s<<6) | L];
        float nn = v.x*v.x + v.y*v.y + v.z*v.z + v.w*v.w;
        float dp = q.x*v.x + q.y*v.y + q.z*v.z + q.w*v.w;
        d[s] = nn - 2.f*dp;   // |xn|^2 dropped: rank-equivalent
    }
    const float MX = 3.4e38f;
    float m1 = MX, m2 = MX; int i1 = 0, i2 = 0;
    #pragma unroll
    for (int j = 0; j < 64; ++j) {
        float v = d[j];
        bool c1 = v < m1, c2 = v < m2;
        m2 = c1 ? m1 : (c2 ? v : m2);
        i2 = c1 ? i1 : (c2 ? j : i2);
        m1 = c1 ? v : m1;
        i1 = c1 ? j : i1;
    }
    bool have2 = true;
    unsigned long long used = 0;
    int mywin = 0;
    for (int r = 0; r < K_; ++r) {
        float bv = m1; int bg = (i1<<6) | L;
        #pragma unroll
        for (int off = 32; off; off >>= 1) {
            float ov = __shfl_xor(bv, off);
            int   og = __shfl_xor(bg, off);
            bool tk = (ov < bv) || (ov == bv && og < bg);
            bv = tk ? ov : bv; bg = tk ? og : bg;
        }
        if (L == r) mywin = bg;
        if (L == (bg & 63)) {
            used |= 1ull << i1;
            if (have2) { m1 = m2; i1 = i2; have2 = false; }
            else {
                m1 = MX; m2 = MX; i1 = 0; i2 = 0;
                #pragma unroll
                for (int j = 0; j < 64; ++j) {
                    float v = ((used >> j) & 1ull) ? MX : d[j];
                    bool c1 = v < m1, c2 = v < m2;
                    m2 = c1 ? m1 : (c2 ? v : m2);
                    i2 = c1 ? i1 : (c2 ? j : i2);
                    m1 = c1 ? v : m1;
                    i1 = c1 ? j : i1;
                }
                have2 = true;
            }
        }
    }
    if (L < K_) idxout[(b*N_ + n)*K_ + L] = mywin;
}

// ---------------------------------------------------------------- prep: fp32 -> split bf16 (hi+lo) + sq norms
static __device__ inline unsigned short f2bf(float f)
{
    unsigned u = __float_as_uint(f);
    unsigned r = (u + 0x7fffu + ((u >> 16) & 1u)) >> 16;   // RNE
    return (unsigned short)r;
}

__global__ __launch_bounds__(256) void prep64_kernel(const float* __restrict__ x,
                                                     unsigned short* __restrict__ Xh,
                                                     unsigned short* __restrict__ Xl,
                                                     float* __restrict__ nrm)
{
    const int t = threadIdx.x, L = t & 63;
    const int row = blockIdx.x*4 + (t >> 6);
    const float v = x[row*64 + L];
    unsigned short h = f2bf(v);
    float hf = __uint_as_float((unsigned)h << 16);
    unsigned short l = f2bf(v - hf);
    Xh[row*64 + L] = h;
    Xl[row*64 + L] = l;
    float s = v * v;
    #pragma unroll
    for (int off = 32; off; off >>= 1) s += __shfl_xor(s, off);
    if (L == 0) nrm[row] = s;
}

// ---------------------------------------------------------------- kNN, C=64 via MFMA (split-bf16 Gram, approx)
// Selects top-KS_ (=24) approximate neighbors; exact fp32 rescore trims to 20.
__global__ __launch_bounds__(256) void knn64v2_kernel(
    const unsigned short* __restrict__ Xh, const unsigned short* __restrict__ Xl,
    const float* __restrict__ nrm, int* __restrict__ idx24)
{
    __shared__ float dist[16*1024];   // exactly 64 KB; the only LDS in this kernel
    const int b = blockIdx.y, t = threadIdx.x;
    const int w = t >> 6, L = t & 63;
    const int q0 = blockIdx.x * 16;
    const int m = L & 15, kq = (L >> 4) * 8;
    const size_t rowbase = (size_t)b * N_ * 64;

    // A fragments (16 query rows), kept in registers for the whole kernel
    const unsigned short* aph = Xh + rowbase + (size_t)(q0 + m)*64 + kq;
    const unsigned short* apl = Xl + rowbase + (size_t)(q0 + m)*64 + kq;
    const bf16x8 a_h0 = *(const bf16x8*)(aph);
    const bf16x8 a_h1 = *(const bf16x8*)(aph + 32);
    const bf16x8 a_l0 = *(const bf16x8*)(apl);
    const bf16x8 a_l1 = *(const bf16x8*)(apl + 32);

    const float MX = 3.4e38f;
    float sv[4][4];  int si[4][4];    // [query-in-wave][chunk] winners (lanes 0..KS_-1)
    #pragma unroll
    for (int a = 0; a < 4; ++a)
        #pragma unroll
        for (int c = 0; c < 4; ++c) { sv[a][c] = MX; si[a][c] = 0x7fffffff; }

    #pragma unroll
    for (int ck = 0; ck < 4; ++ck) {
        const int cq = ck * 1024;
        __syncthreads();              // previous chunk's selection done
        for (int tt = 0; tt < 16; ++tt) {
            const int cbase = cq + w*256 + tt*16;
            const unsigned short* bph = Xh + rowbase + (size_t)(cbase + m)*64 + kq;
            const unsigned short* bpl = Xl + rowbase + (size_t)(cbase + m)*64 + kq;
            bf16x8 b_h0 = *(const bf16x8*)(bph);
            bf16x8 b_h1 = *(const bf16x8*)(bph + 32);
            bf16x8 b_l0 = *(const bf16x8*)(bpl);
            bf16x8 b_l1 = *(const bf16x8*)(bpl + 32);
            f32x4 acc = {0.f, 0.f, 0.f, 0.f};
            acc = __builtin_amdgcn_mfma_f32_16x16x32_bf16(a_h0, b_h0, acc, 0, 0, 0);
            acc = __builtin_amdgcn_mfma_f32_16x16x32_bf16(a_h1, b_h1, acc, 0, 0, 0);
            acc = __builtin_amdgcn_mfma_f32_16x16x32_bf16(a_l0, b_h0, acc, 0, 0, 0);
            acc = __builtin_amdgcn_mfma_f32_16x16x32_bf16(a_l1, b_h1, acc, 0, 0, 0);
            acc = __builtin_amdgcn_mfma_f32_16x16x32_bf16(a_h0, b_l0, acc, 0, 0, 0);
            acc = __builtin_amdgcn_mfma_f32_16x16x32_bf16(a_h1, b_l1, acc, 0, 0, 0);
            const float nv = nrm[b*N_ + cbase + m];
            const int lc = w*256 + tt*16 + m;          // physical col in chunk
            #pragma unroll
            for (int r = 0; r < 4; ++r) {
                const int qrow = (L >> 4)*4 + r;       // C/D layout: row=(lane>>4)*4+reg
                dist[qrow*1024 + lc] = nv - 2.f*acc[r];
            }
        }
        __syncthreads();
        // selection: wave w owns queries w*4 + qi; top-KS_ of this chunk
        #pragma unroll
        for (int qi = 0; qi < 4; ++qi) {
            const float* dw = dist + (w*4 + qi)*1024;
            float m1 = MX, m2 = MX; int i1 = 0, i2 = 0;
            #pragma unroll
            for (int j = 0; j < 16; ++j) {
                float v = dw[(j<<6) | L];
                bool c1 = v < m1, c2 = v < m2;
                m2 = c1 ? m1 : (c2 ? v : m2);
                i2 = c1 ? i1 : (c2 ? j : i2);
                m1 = c1 ? v : m1;
                i1 = c1 ? j : i1;
            }
            bool have2 = true;
            unsigned used = 0;
            for (int r = 0; r < KS_; ++r) {
                float bv = m1; int bg = (i1<<6) | L;
                #pragma unroll
                for (int off = 32; off; off >>= 1) {
                    float ov = __shfl_xor(bv, off);
                    int   og = __shfl_xor(bg, off);
                    bool tk = (ov < bv) || (ov == bv && og < bg);
                    bv = tk ? ov : bv; bg = tk ? og : bg;
                }
                if (L == r) { sv[qi][ck] = bv; si[qi][ck] = cq + bg; }
                if (L == (bg & 63)) {
                    used |= 1u << i1;
                    if (have2) { m1 = m2; i1 = i2; have2 = false; }
                    else {
                        m1 = MX; m2 = MX; i1 = 0; i2 = 0;
                        #pragma unroll
                        for (int j = 0; j < 16; ++j) {
                            float v = ((used >> j) & 1u) ? MX : dw[(j<<6) | L];
                            bool c1 = v < m1, c2 = v < m2;
                            m2 = c1 ? m1 : (c2 ? v : m2);
                            i2 = c1 ? i1 : (c2 ? j : i2);
                            m1 = c1 ? v : m1;
                            i1 = c1 ? j : i1;
                        }
                        have2 = true;
                    }
                }
            }
        }
    }
    // merge the 4 per-chunk top-KS_ lists (lanes 0..KS_-1 x 4 slots)
    #pragma unroll
    for (int qi = 0; qi < 4; ++qi) {
        int myfin = 0;
        for (int r = 0; r < KS_; ++r) {
            float lv = sv[qi][0]; int li = si[qi][0];
            #pragma unroll
            for (int c = 1; c < 4; ++c) {
                bool tk = (sv[qi][c] < lv) || (sv[qi][c] == lv && si[qi][c] < li);
                lv = tk ? sv[qi][c] : lv; li = tk ? si[qi][c] : li;
            }
            #pragma unroll
            for (int off = 32; off; off >>= 1) {
                float ov = __shfl_xor(lv, off);
                int   oi = __shfl_xor(li, off);
                bool tk = (ov < lv) || (ov == lv && oi < li);
                lv = tk ? ov : lv; li = tk ? oi : li;
            }
            if (L == r) myfin = li;
            #pragma unroll
            for (int c = 0; c < 4; ++c)
                if (si[qi][c] == li) sv[qi][c] = MX;
        }
        if (L < KS_) idx24[((size_t)b*N_ + q0 + w*4 + qi)*KS_ + L] = myfin;
    }
}

// ---------------------------------------------------------------- exact fp32 rescore of the KS_ candidates
// One wave per query: lanes 0..KS_-1 compute exact dists; 20 wave-argmin rounds.
__global__ __launch_bounds__(256) void rescore_kernel(const float* __restrict__ x1, const float* __restrict__ nrm,
                                                      const int* __restrict__ idx24, int* __restrict__ idxout)
{
    const int t = threadIdx.x, w = t >> 6, L = t & 63;
    const int p = blockIdx.x*4 + w;
    const int bbase = p & ~(N_-1);
    const float MX = 3.4e38f;
    float dv = MX; int di = 0x7fffffff;
    if (L < KS_) {
        const int ci = idx24[(size_t)p*KS_ + L];
        const float4* qr = (const float4*)(x1 + (size_t)p*64);
        const float4* cr = (const float4*)(x1 + (size_t)(bbase + ci)*64);
        float dot = 0.f;
        #pragma unroll
        for (int i = 0; i < 16; ++i) {
            float4 a = qr[i], bx = cr[i];
            dot += a.x*bx.x + a.y*bx.y + a.z*bx.z + a.w*bx.w;
        }
        dv = nrm[bbase + ci] - 2.f*dot;   // query norm dropped: rank-equivalent
        di = ci;
    }
    int myfin = 0;
    for (int r = 0; r < K_; ++r) {
        float bv = dv; int bg = di;
        #pragma unroll
        for (int off = 32; off; off >>= 1) {
            float ov = __shfl_xor(bv, off);
            int   og = __shfl_xor(bg, off);
            bool tk = (ov < bv) || (ov == bv && og < bg);
            bv = tk ? ov : bv; bg = tk ? og : bg;
        }
        if (L == r) myfin = bg;
        if (di == bg) dv = MX;           // remove winner (indices unique per query)
    }
    if (L < K_) idxout[(size_t)p*K_ + L] = myfin;
}

// ---------------------------------------------------------------- P/Q precompute
__global__ __launch_bounds__(256) void pq1_kernel(const float* __restrict__ x, const float* __restrict__ W,
                                                  const float* __restrict__ b1,
                                                  float* __restrict__ P, float* __restrict__ Q)
{
    __shared__ float wd[256], wb[256];
    const int t = threadIdx.x;
    wd[t] = W[t] - W[256 + t];
    wb[t] = W[256 + t];
    __syncthreads();
    const int p = blockIdx.x*4 + (t >> 6), c = t & 63;
    const float4 xv = ((const float4*)x)[p];
    float Pv = b1[c] + xv.x*wd[c] + xv.y*wd[64+c] + xv.z*wd[128+c] + xv.w*wd[192+c];
    float Qv =         xv.x*wb[c] + xv.y*wb[64+c] + xv.z*wb[128+c] + xv.w*wb[192+c];
    P[p*64 + c] = Pv;
    Q[p*64 + c] = Qv;
}

__global__ __launch_bounds__(256) void pq2_kernel(const float* __restrict__ x1, const float* __restrict__ W,
                                                  const float* __restrict__ b1,
                                                  float* __restrict__ P, float* __restrict__ Q)
{
    __shared__ float wd[64*128], wb[64*128];
    const int t = threadIdx.x;
    for (int e = t; e < 8192; e += 256) {
        float wt = W[e], wbo = W[8192 + e];
        wd[e] = wt - wbo; wb[e] = wbo;
    }
    __syncthreads();
    const int pl = t >> 7, c = t & 127;
    const float b1v = b1[c];
    for (int p0 = blockIdx.x*2; p0 < BN_; p0 += gridDim.x*2) {
        const int p = p0 + pl;
        float Pv = b1v, Qv = 0.f;
        const float* xrow = x1 + p*64;
        #pragma unroll 8
        for (int k = 0; k < 64; ++k) {
            float xv = xrow[k];
            Pv += xv * wd[k*128 + c];
            Qv += xv * wb[k*128 + c];
        }
        P[p*128 + c] = Pv;
        Q[p*128 + c] = Qv;
    }
}

// ---------------------------------------------------------------- layer-1 BN stats
template<int HO>
__global__ __launch_bounds__(256) void stats_l1_kernel(const float* __restrict__ P, const float* __restrict__ Q,
                                                       const int* __restrict__ idx, float* __restrict__ stOut)
{
    constexpr int G = 256/HO;
    __shared__ float red[256], red2[256];
    const int t = threadIdx.x, c = t % HO, g = t / HO;
    float s = 0.f, s2 = 0.f;
    for (int p = blockIdx.x; p < BN_; p += gridDim.x) {
        const float Pv = P[p*HO + c];
        const int bbase = p & ~(N_-1);
        for (int j = g; j < K_; j += G) {
            int m = idx[p*K_ + j];
            float z = Pv + Q[(bbase + m)*HO + c];
            s += z; s2 += z*z;
        }
    }
    red[t] = s; red2[t] = s2;
    __syncthreads();
    if (t < HO) {
        float a = red[t], a2 = red2[t];
        #pragma unroll
        for (int q = 1; q < G; ++q) { a += red[q*HO + t]; a2 += red2[q*HO + t]; }
        atomicAdd(&stOut[t], a);
        atomicAdd(&stOut[HO + t], a2);
    }
}

// ---------------------------------------------------------------- EdgeConv layer-2
template<int HO>
__global__ __launch_bounds__(256) void conv_l2_kernel(
    const float* __restrict__ P, const float* __restrict__ Q, const int* __restrict__ idx,
    const float* __restrict__ st1, const float* __restrict__ g1, const float* __restrict__ be1,
    const float* __restrict__ w2, const float* __restrict__ b2,
    float* __restrict__ zmax, float* __restrict__ zmin, float* __restrict__ stOut)
{
    __shared__ float w2s[HO*64];
    __shared__ float h1s[K_*HO];
    __shared__ float redA[256], redB[256];
    const int t = threadIdx.x;
    const int cy = blockIdx.y;
    for (int e = t; e < HO*64; e += 256) {
        int c = e >> 6, cl = e & 63;
        w2s[e] = w2[c*HO + cy*64 + cl];
    }
    const int cA = t % HO;
    const float ac = st1[3*HO + cA] * g1[cA];
    const float bc = be1[cA] - st1[2*HO + cA] * ac;
    const int c2l = t & 63, jh = t >> 6;
    const float b2v = b2[cy*64 + c2l];
    float ssum = 0.f, ssq = 0.f;
    for (int p = blockIdx.x; p < BN_; p += gridDim.x) {
        __syncthreads();
        const int bbase = p & ~(N_-1);
        const float Pv = P[p*HO + cA];
        for (int e = t; e < K_*HO; e += 256) {
            int j = e / HO;
            int m = idx[p*K_ + j];
            float z = Pv + Q[(bbase + m)*HO + cA];
            h1s[e] = fmaxf(z*ac + bc, 0.f);
        }
        __syncthreads();
        float acc[5];
        #pragma unroll
        for (int q = 0; q < 5; ++q) acc[q] = b2v;
        for (int c = 0; c < HO; ++c) {
            float wv = w2s[c*64 + c2l];
            #pragma unroll
            for (int q = 0; q < 5; ++q)
                acc[q] += h1s[(jh + q*4)*HO + c] * wv;
        }
        float mx = acc[0], mn = acc[0];
        #pragma unroll
        for (int q = 0; q < 5; ++q) {
            mx = fmaxf(mx, acc[q]); mn = fminf(mn, acc[q]);
            ssum += acc[q]; ssq += acc[q]*acc[q];
        }
        redA[t] = mx; redB[t] = mn;
        __syncthreads();
        if (t < 64) {
            float M = redA[t], Mn = redB[t];
            #pragma unroll
            for (int g = 1; g < 4; ++g) { M = fmaxf(M, redA[g*64 + t]); Mn = fminf(Mn, redB[g*64 + t]); }
            zmax[p*HO + cy*64 + t] = M;
            zmin[p*HO + cy*64 + t] = Mn;
        }
    }
    __syncthreads();
    redA[t] = ssum; redB[t] = ssq;
    __syncthreads();
    if (t < 64) {
        float s = redA[t], s2 = redB[t];
        #pragma unroll
        for (int g = 1; g < 4; ++g) { s += redA[g*64 + t]; s2 += redB[g*64 + t]; }
        atomicAdd(&stOut[cy*64 + t], s);
        atomicAdd(&stOut[HO + cy*64 + t], s2);
    }
}

template<int HO>
__global__ __launch_bounds__(256) void conv_fin_kernel(
    const float* __restrict__ zmax, const float* __restrict__ zmin,
    const float* __restrict__ st2, const float* __restrict__ g2, const float* __restrict__ be2,
    float* __restrict__ out)
{
    int e = blockIdx.x*256 + threadIdx.x;
    int c = e & (HO-1);
    float g = g2[c];
    float a = st2[3*HO + c] * g;
    float sel = (g >= 0.f) ? zmax[e] : zmin[e];
    out[e] = fmaxf((sel - st2[2*HO + c]) * a + be2[c], 0.f);
}

// ---------------------------------------------------------------- classifier
__global__ __launch_bounds__(256) void cls1_kernel(
    const float* __restrict__ x1, const float* __restrict__ x2f,
    const float* __restrict__ W, const float* __restrict__ b1,
    float* __restrict__ z, float* __restrict__ stOut)
{
    __shared__ float ws[192*64];
    __shared__ float xr[4*192];
    __shared__ float red[256], red2[256];
    const int t = threadIdx.x, cy = blockIdx.y;
    for (int e = t; e < 192*64; e += 256) {
        int c = e >> 6, cl = e & 63;
        ws[e] = W[c*128 + cy*64 + cl];
    }
    const int pl = t >> 6, c2l = t & 63;
    const float b1v = b1[cy*64 + c2l];
    float ssum = 0.f, ssq = 0.f;
    for (int p0 = blockIdx.x*4; p0 < BN_; p0 += gridDim.x*4) {
        __syncthreads();
        for (int l = t; l < 4*192; l += 256) {
            int pp = l / 192, cc = l % 192;
            xr[l] = (cc < 64) ? x1[(p0+pp)*64 + cc] : x2f[(p0+pp)*128 + cc - 64];
        }
        __syncthreads();
        float acc = b1v;
        const float* xx = xr + pl*192;
        #pragma unroll 8
        for (int c = 0; c < 192; ++c) acc += xx[c] * ws[c*64 + c2l];
        z[(p0+pl)*128 + cy*64 + c2l] = acc;
        ssum += acc; ssq += acc*acc;
    }
    __syncthreads();
    red[t] = ssum; red2[t] = ssq;
    __syncthreads();
    if (t < 64) {
        float s = red[t], s2 = red2[t];
        #pragma unroll
        for (int g = 1; g < 4; ++g) { s += red[g*64 + t]; s2 += red2[g*64 + t]; }
        atomicAdd(&stOut[cy*64 + t], s);
        atomicAdd(&stOut[128 + cy*64 + t], s2);
    }
}

__global__ __launch_bounds__(256) void cls_fin_kernel(
    const float* __restrict__ z, const float* __restrict__ st,
    const float* __restrict__ g, const float* __restrict__ be,
    const float* __restrict__ w2, const float* __restrict__ b2,
    float* __restrict__ out)
{
    const int t = threadIdx.x, w = t >> 6, L = t & 63;
    const int p = blockIdx.x*4 + w;
    float s = 0.f;
    #pragma unroll
    for (int h = 0; h < 2; ++h) {
        int c = L + h*64;
        float v = (z[p*128 + c] - st[256 + c]) * st[384 + c] * g[c] + be[c];
        s += fmaxf(v, 0.f) * w2[c];
    }
    #pragma unroll
    for (int off = 32; off; off >>= 1) s += __shfl_xor(s, off);
    if (L == 0) out[p] = s + b2[0];
}

// ---------------------------------------------------------------- launch
extern "C" void kernel_launch(void* const* d_in, const int* in_sizes, int n_in,
                              void* d_out, int out_size, void* d_ws, size_t ws_size,
                              hipStream_t stream)
{
    const float* x      = (const float*)d_in[0];
    const float* c1_w1  = (const float*)d_in[1];
    const float* c1_b1  = (const float*)d_in[2];
    const float* c1_g1  = (const float*)d_in[3];
    const float* c1_be1 = (const float*)d_in[4];
    const float* c1_w2  = (const float*)d_in[5];
    const float* c1_b2  = (const float*)d_in[6];
    const float* c1_g2  = (const float*)d_in[7];
    const float* c1_be2 = (const float*)d_in[8];
    const float* c2_w1  = (const float*)d_in[9];
    const float* c2_b1  = (const float*)d_in[10];
    const float* c2_g1  = (const float*)d_in[11];
    const float* c2_be1 = (const float*)d_in[12];
    const float* c2_w2  = (const float*)d_in[13];
    const float* c2_b2  = (const float*)d_in[14];
    const float* c2_g2  = (const float*)d_in[15];
    const float* c2_be2 = (const float*)d_in[16];
    const float* cls_w1 = (const float*)d_in[17];
    const float* cls_b1 = (const float*)d_in[18];
    const float* cls_g1 = (const float*)d_in[19];
    const float* cls_be1= (const float*)d_in[20];
    const float* cls_w2 = (const float*)d_in[21];
    const float* cls_b2 = (const float*)d_in[22];
    (void)in_sizes; (void)n_in; (void)out_size; (void)ws_size;

    char* ws = (char*)d_ws;
    size_t off = 0;
    auto alloc = [&](size_t bytes) { char* p = ws + off; off += (bytes + 255) & ~255ull; return p; };
    float* A    = (float*)alloc((size_t)16<<20);   // P1 -> P2 -> zcls
    float* Bq   = (float*)alloc((size_t)16<<20);   // Q1 -> Q2
    float* zmax = (float*)alloc((size_t)16<<20);   // also hosts Xh/Xl between conv1 and conv2
    float* zmin = (float*)alloc((size_t)16<<20);
    float* x1b  = (float*)alloc((size_t)8<<20);
    float* x2b  = (float*)alloc((size_t)16<<20);   // also hosts idx24 during kNN2 phase
    int*   idx  = (int*)  alloc((size_t)BN_*K_*4); // idx1 -> idx2
    float* nrm  = (float*)alloc((size_t)BN_*4);
    float* st   = (float*)alloc((size_t)5*512*4);
    float *st0 = st, *st1 = st+512, *st2 = st+1024, *st3 = st+1536, *st4 = st+2048;

    // split-bf16 feature buffers alias zmax (dead between conv_fin<64> and conv_l2<128>)
    unsigned short* Xh = (unsigned short*)zmax;                       // 4 MB
    unsigned short* Xl = (unsigned short*)((char*)zmax + (4<<20));    // 4 MB
    // approx top-24 indices alias x2b (dead until conv_fin<128>)
    int* idx24 = (int*)x2b;                                           // 3.1 MB

    zero_kernel<<<1, 256, 0, stream>>>(st, 5*512);

    // ---- EdgeConv 1
    knn4_kernel<<<dim3(N_/16, B_), 1024, 0, stream>>>(x, idx);
    pq1_kernel<<<BN_/4, 256, 0, stream>>>(x, c1_w1, c1_b1, A, Bq);
    stats_l1_kernel<64><<<2048, 256, 0, stream>>>(A, Bq, idx, st0);
    finalize_kernel<<<1, 128, 0, stream>>>(st0, 64, 1.f/655360.f);
    conv_l2_kernel<64><<<dim3(2048,1), 256, 0, stream>>>(A, Bq, idx, st0, c1_g1, c1_be1, c1_w2, c1_b2, zmax, zmin, st1);
    finalize_kernel<<<1, 128, 0, stream>>>(st1, 64, 1.f/655360.f);
    conv_fin_kernel<64><<<BN_*64/256, 256, 0, stream>>>(zmax, zmin, st1, c1_g2, c1_be2, x1b);

    // ---- EdgeConv 2
    prep64_kernel<<<BN_/4, 256, 0, stream>>>(x1b, Xh, Xl, nrm);
    knn64v2_kernel<<<dim3(N_/16, B_), 256, 0, stream>>>(Xh, Xl, nrm, idx24);
    rescore_kernel<<<BN_/4, 256, 0, stream>>>(x1b, nrm, idx24, idx);
    pq2_kernel<<<1024, 256, 0, stream>>>(x1b, c2_w1, c2_b1, A, Bq);
    stats_l1_kernel<128><<<2048, 256, 0, stream>>>(A, Bq, idx, st2);
    finalize_kernel<<<1, 128, 0, stream>>>(st2, 128, 1.f/655360.f);
    conv_l2_kernel<128><<<dim3(2048,2), 256, 0, stream>>>(A, Bq, idx, st2, c2_g1, c2_be1, c2_w2, c2_b2, zmax, zmin, st3);
    finalize_kernel<<<1, 128, 0, stream>>>(st3, 128, 1.f/655360.f);
    conv_fin_kernel<128><<<BN_*128/256, 256, 0, stream>>>(zmax, zmin, st3, c2_g2, c2_be2, x2b);

    // ---- classifier
    cls1_kernel<<<dim3(512,2), 256, 0, stream>>>(x1b, x2b, cls_w1, cls_b1, A, st4);
    finalize_kernel<<<1, 128, 0, stream>>>(st4, 128, 1.f/32768.f);
    cls_fin_kernel<<<BN_/4, 256, 0, stream>>>(A, st4, cls_g1, cls_be1, cls_w2, cls_b2, (float*)d_out);
}

// Round 5
// 2447.198 us; speedup vs baseline: 1.2648x; 1.2648x over previous
//
#include <hip/hip_runtime.h>
#include <math.h>

#define B_ 8
#define N_ 4096
#define K_ 20
#define KS_ 28          // approx-select width; exact rescore trims to K_
#define BN_ (B_*N_)

typedef __attribute__((ext_vector_type(8))) short bf16x8;
typedef __attribute__((ext_vector_type(4))) float f32x4;

// ---------------------------------------------------------------- utilities
__global__ void zero_kernel(float* p, int n)
{
    for (int e = threadIdx.x; e < n; e += 256) p[e] = 0.f;
}

// mean/rstd from accumulated sum/sumsq.  layout: [sum(H), sumsq(H), mean(H), rstd(H)]
__global__ void finalize_kernel(float* st, int H, float invCount)
{
    int t = threadIdx.x;
    if (t < H) {
        float mean = st[t] * invCount;
        float var  = fmaxf(st[H + t] * invCount - mean * mean, 0.f);
        st[2*H + t] = mean;
        st[3*H + t] = 1.f / sqrtf(var + 1e-5f);
    }
}

// ---------------------------------------------------------------- kNN, C=4
__global__ __launch_bounds__(1024) void knn4_kernel(const float* __restrict__ x, int* __restrict__ idxout)
{
    __shared__ float4 xt[N_];
    const int b = blockIdx.y;
    const int t = threadIdx.x;
    const float4* xg = (const float4*)x + b*N_;
    for (int e = t; e < N_; e += 1024) xt[e] = xg[e];
    __syncthreads();
    const int w = t >> 6, L = t & 63;
    const int n = blockIdx.x*16 + w;
    const float4 q = xt[n];
    float d[64];
    #pragma unroll
    for (int s = 0; s < 64; ++s) {
        float4 v = xt[(s<<6) | L];
        float nn = v.x*v.x + v.y*v.y + v.z*v.z + v.w*v.w;
        float dp = q.x*v.x + q.y*v.y + q.z*v.z + q.w*v.w;
        d[s] = nn - 2.f*dp;   // |xn|^2 dropped: rank-equivalent
    }
    const float MX = 3.4e38f;
    float m1 = MX, m2 = MX; int i1 = 0, i2 = 0;
    #pragma unroll
    for (int j = 0; j < 64; ++j) {
        float v = d[j];
        bool c1 = v < m1, c2 = v < m2;
        m2 = c1 ? m1 : (c2 ? v : m2);
        i2 = c1 ? i1 : (c2 ? j : i2);
        m1 = c1 ? v : m1;
        i1 = c1 ? j : i1;
    }
    bool have2 = true;
    unsigned long long used = 0;
    int mywin = 0;
    for (int r = 0; r < K_; ++r) {
        float bv = m1; int bg = (i1<<6) | L;
        #pragma unroll
        for (int off = 32; off; off >>= 1) {
            float ov = __shfl_xor(bv, off);
            int   og = __shfl_xor(bg, off);
            bool tk = (ov < bv) || (ov == bv && og < bg);
            bv = tk ? ov : bv; bg = tk ? og : bg;
        }
        if (L == r) mywin = bg;
        if (L == (bg & 63)) {
            used |= 1ull << i1;
            if (have2) { m1 = m2; i1 = i2; have2 = false; }
            else {
                m1 = MX; m2 = MX; i1 = 0; i2 = 0;
                #pragma unroll
                for (int j = 0; j < 64; ++j) {
                    float v = ((used >> j) & 1ull) ? MX : d[j];
                    bool c1 = v < m1, c2 = v < m2;
                    m2 = c1 ? m1 : (c2 ? v : m2);
                    i2 = c1 ? i1 : (c2 ? j : i2);
                    m1 = c1 ? v : m1;
                    i1 = c1 ? j : i1;
                }
                have2 = true;
            }
        }
    }
    if (L < K_) idxout[(b*N_ + n)*K_ + L] = mywin;
}

// ---------------------------------------------------------------- prep: fp32 -> split bf16 (hi+lo) + sq norms
static __device__ inline unsigned short f2bf(float f)
{
    unsigned u = __float_as_uint(f);
    unsigned r = (u + 0x7fffu + ((u >> 16) & 1u)) >> 16;   // RNE
    return (unsigned short)r;
}

__global__ __launch_bounds__(256) void prep64_kernel(const float* __restrict__ x,
                                                     unsigned short* __restrict__ Xh,
                                                     unsigned short* __restrict__ Xl,
                                                     float* __restrict__ nrm)
{
    const int t = threadIdx.x, L = t & 63;
    const int row = blockIdx.x*4 + (t >> 6);
    const float v = x[row*64 + L];
    unsigned short h = f2bf(v);
    float hf = __uint_as_float((unsigned)h << 16);
    unsigned short l = f2bf(v - hf);
    Xh[row*64 + L] = h;
    Xl[row*64 + L] = l;
    float s = v * v;
    #pragma unroll
    for (int off = 32; off; off >>= 1) s += __shfl_xor(s, off);
    if (L == 0) nrm[row] = s;
}

// ---------------------------------------------------------------- kNN, C=64 via MFMA (split-bf16 Gram, approx)
// v4: 1024 threads = 16 waves = 16 DISTINCT queries (A-frags & store phase are
// bit-identical to the R3-validated v2 kernel: no A-row duplication, all-lane
// stores).  Per 1024-chunk each wave MFMAs its 64-candidate slice into the
// 16x1024 LDS tile; wave w then copies row w (its query) into registers.
// After 4 chunks: one register-resident top-KS_ selection per wave (knn4
// pattern).  Exact fp32 rescore trims KS_ -> 20.
__global__ __launch_bounds__(1024, 4) void knn64v4_kernel(
    const unsigned short* __restrict__ Xh, const unsigned short* __restrict__ Xl,
    const float* __restrict__ nrm, int* __restrict__ idx24)
{
    __shared__ float dist[16*1024];   // exactly 64 KB; the only LDS in this kernel
    const int b = blockIdx.y, t = threadIdx.x;
    const int w = t >> 6, L = t & 63;          // 16 waves; wave w owns query q0+w
    const int q0 = blockIdx.x * 16;
    const int m = L & 15, kq = (L >> 4) * 8;
    const size_t rowbase = (size_t)b * N_ * 64;

    // A fragments (16 distinct query rows) — identical to validated v2
    const unsigned short* aph = Xh + rowbase + (size_t)(q0 + m)*64 + kq;
    const unsigned short* apl = Xl + rowbase + (size_t)(q0 + m)*64 + kq;
    const bf16x8 a_h0 = *(const bf16x8*)(aph);
    const bf16x8 a_h1 = *(const bf16x8*)(aph + 32);
    const bf16x8 a_l0 = *(const bf16x8*)(apl);
    const bf16x8 a_l1 = *(const bf16x8*)(apl + 32);

    float d[64];                       // dists for query q0+w, cand = (j<<6)|L
    #pragma unroll
    for (int ck = 0; ck < 4; ++ck) {
        const int cq = ck * 1024;
        __syncthreads();               // previous chunk's readback complete
        for (int tt = 0; tt < 4; ++tt) {
            const int cbase = w*64 + tt*16;    // chunk-local candidate base
            const unsigned short* bph = Xh + rowbase + (size_t)(cq + cbase + m)*64 + kq;
            const unsigned short* bpl = Xl + rowbase + (size_t)(cq + cbase + m)*64 + kq;
            bf16x8 b_h0 = *(const bf16x8*)(bph);
            bf16x8 b_h1 = *(const bf16x8*)(bph + 32);
            bf16x8 b_l0 = *(const bf16x8*)(bpl);
            bf16x8 b_l1 = *(const bf16x8*)(bpl + 32);
            f32x4 acc = {0.f, 0.f, 0.f, 0.f};
            acc = __builtin_amdgcn_mfma_f32_16x16x32_bf16(a_h0, b_h0, acc, 0, 0, 0);
            acc = __builtin_amdgcn_mfma_f32_16x16x32_bf16(a_h1, b_h1, acc, 0, 0, 0);
            acc = __builtin_amdgcn_mfma_f32_16x16x32_bf16(a_l0, b_h0, acc, 0, 0, 0);
            acc = __builtin_amdgcn_mfma_f32_16x16x32_bf16(a_l1, b_h1, acc, 0, 0, 0);
            acc = __builtin_amdgcn_mfma_f32_16x16x32_bf16(a_h0, b_l0, acc, 0, 0, 0);
            acc = __builtin_amdgcn_mfma_f32_16x16x32_bf16(a_h1, b_l1, acc, 0, 0, 0);
            // store phase identical to validated v2: ALL lanes write
            const float nv = nrm[b*N_ + cq + cbase + m];
            #pragma unroll
            for (int r = 0; r < 4; ++r) {
                const int qrow = (L >> 4)*4 + r;   // C/D layout: row=(lane>>4)*4+reg
                dist[qrow*1024 + cbase + m] = nv - 2.f*acc[r];
            }
        }
        __syncthreads();               // dist tile complete
        #pragma unroll
        for (int s = 0; s < 16; ++s)
            d[ck*16 + s] = dist[w*1024 + (s<<6) + L];
    }

    // register-resident top-KS_ selection (knn4 pattern), cand index = (j<<6)|L
    const float MX = 3.4e38f;
    float m1 = MX, m2 = MX; int i1 = 0, i2 = 0;
    #pragma unroll
    for (int j = 0; j < 64; ++j) {
        float v = d[j];
        bool c1 = v < m1, c2 = v < m2;
        m2 = c1 ? m1 : (c2 ? v : m2);
        i2 = c1 ? i1 : (c2 ? j : i2);
        m1 = c1 ? v : m1;
        i1 = c1 ? j : i1;
    }
    bool have2 = true;
    unsigned long long used = 0;
    int mywin = 0;
    for (int r = 0; r < KS_; ++r) {
        float bv = m1; int bg = (i1<<6) | L;
        #pragma unroll
        for (int off = 32; off; off >>= 1) {
            float ov = __shfl_xor(bv, off);
            int   og = __shfl_xor(bg, off);
            bool tk = (ov < bv) || (ov == bv && og < bg);
            bv = tk ? ov : bv; bg = tk ? og : bg;
        }
        if (L == r) mywin = bg;
        if (L == (bg & 63)) {
            used |= 1ull << i1;
            if (have2) { m1 = m2; i1 = i2; have2 = false; }
            else {
                m1 = MX; m2 = MX; i1 = 0; i2 = 0;
                #pragma unroll
                for (int j = 0; j < 64; ++j) {
                    float v = ((used >> j) & 1ull) ? MX : d[j];
                    bool c1 = v < m1, c2 = v < m2;
                    m2 = c1 ? m1 : (c2 ? v : m2);
                    i2 = c1 ? i1 : (c2 ? j : i2);
                    m1 = c1 ? v : m1;
                    i1 = c1 ? j : i1;
                }
                have2 = true;
            }
        }
    }
    if (L < KS_) idx24[((size_t)b*N_ + q0 + w)*KS_ + L] = mywin;
}

// ---------------------------------------------------------------- exact fp32 rescore of the KS_ candidates
// One wave per query: lanes 0..KS_-1 compute exact dists; 20 wave-argmin rounds.
__global__ __launch_bounds__(256) void rescore_kernel(const float* __restrict__ x1, const float* __restrict__ nrm,
                                                      const int* __restrict__ idx24, int* __restrict__ idxout)
{
    const int t = threadIdx.x, w = t >> 6, L = t & 63;
    const int p = blockIdx.x*4 + w;
    const int bbase = p & ~(N_-1);
    const float MX = 3.4e38f;
    float dv = MX; int di = 0x7fffffff;
    if (L < KS_) {
        const int ci = idx24[(size_t)p*KS_ + L];
        const float4* qr = (const float4*)(x1 + (size_t)p*64);
        const float4* cr = (const float4*)(x1 + (size_t)(bbase + ci)*64);
        float dot = 0.f;
        #pragma unroll
        for (int i = 0; i < 16; ++i) {
            float4 a = qr[i], bx = cr[i];
            dot += a.x*bx.x + a.y*bx.y + a.z*bx.z + a.w*bx.w;
        }
        dv = nrm[bbase + ci] - 2.f*dot;   // query norm dropped: rank-equivalent
        di = ci;
    }
    int myfin = 0;
    for (int r = 0; r < K_; ++r) {
        float bv = dv; int bg = di;
        #pragma unroll
        for (int off = 32; off; off >>= 1) {
            float ov = __shfl_xor(bv, off);
            int   og = __shfl_xor(bg, off);
            bool tk = (ov < bv) || (ov == bv && og < bg);
            bv = tk ? ov : bv; bg = tk ? og : bg;
        }
        if (L == r) myfin = bg;
        if (di == bg) dv = MX;           // remove winner (indices unique per query)
    }
    if (L < K_) idxout[(size_t)p*K_ + L] = myfin;
}

// ---------------------------------------------------------------- P/Q precompute
__global__ __launch_bounds__(256) void pq1_kernel(const float* __restrict__ x, const float* __restrict__ W,
                                                  const float* __restrict__ b1,
                                                  float* __restrict__ P, float* __restrict__ Q)
{
    __shared__ float wd[256], wb[256];
    const int t = threadIdx.x;
    wd[t] = W[t] - W[256 + t];
    wb[t] = W[256 + t];
    __syncthreads();
    const int p = blockIdx.x*4 + (t >> 6), c = t & 63;
    const float4 xv = ((const float4*)x)[p];
    float Pv = b1[c] + xv.x*wd[c] + xv.y*wd[64+c] + xv.z*wd[128+c] + xv.w*wd[192+c];
    float Qv =         xv.x*wb[c] + xv.y*wb[64+c] + xv.z*wb[128+c] + xv.w*wb[192+c];
    P[p*64 + c] = Pv;
    Q[p*64 + c] = Qv;
}

__global__ __launch_bounds__(256) void pq2_kernel(const float* __restrict__ x1, const float* __restrict__ W,
                                                  const float* __restrict__ b1,
                                                  float* __restrict__ P, float* __restrict__ Q)
{
    __shared__ float wd[64*128], wb[64*128];
    const int t = threadIdx.x;
    for (int e = t; e < 8192; e += 256) {
        float wt = W[e], wbo = W[8192 + e];
        wd[e] = wt - wbo; wb[e] = wbo;
    }
    __syncthreads();
    const int pl = t >> 7, c = t & 127;
    const float b1v = b1[c];
    for (int p0 = blockIdx.x*2; p0 < BN_; p0 += gridDim.x*2) {
        const int p = p0 + pl;
        float Pv = b1v, Qv = 0.f;
        const float* xrow = x1 + p*64;
        #pragma unroll 8
        for (int k = 0; k < 64; ++k) {
            float xv = xrow[k];
            Pv += xv * wd[k*128 + c];
            Qv += xv * wb[k*128 + c];
        }
        P[p*128 + c] = Pv;
        Q[p*128 + c] = Qv;
    }
}

// ---------------------------------------------------------------- layer-1 BN stats
template<int HO>
__global__ __launch_bounds__(256) void stats_l1_kernel(const float* __restrict__ P, const float* __restrict__ Q,
                                                       const int* __restrict__ idx, float* __restrict__ stOut)
{
    constexpr int G = 256/HO;
    __shared__ float red[256], red2[256];
    const int t = threadIdx.x, c = t % HO, g = t / HO;
    float s = 0.f, s2 = 0.f;
    for (int p = blockIdx.x; p < BN_; p += gridDim.x) {
        const float Pv = P[p*HO + c];
        const int bbase = p & ~(N_-1);
        for (int j = g; j < K_; j += G) {
            int m = idx[p*K_ + j];
            float z = Pv + Q[(bbase + m)*HO + c];
            s += z; s2 += z*z;
        }
    }
    red[t] = s; red2[t] = s2;
    __syncthreads();
    if (t < HO) {
        float a = red[t], a2 = red2[t];
        #pragma unroll
        for (int q = 1; q < G; ++q) { a += red[q*HO + t]; a2 += red2[q*HO + t]; }
        atomicAdd(&stOut[t], a);
        atomicAdd(&stOut[HO + t], a2);
    }
}

// ---------------------------------------------------------------- EdgeConv layer-2
template<int HO>
__global__ __launch_bounds__(256) void conv_l2_kernel(
    const float* __restrict__ P, const float* __restrict__ Q, const int* __restrict__ idx,
    const float* __restrict__ st1, const float* __restrict__ g1, const float* __restrict__ be1,
    const float* __restrict__ w2, const float* __restrict__ b2,
    float* __restrict__ zmax, float* __restrict__ zmin, float* __restrict__ stOut)
{
    __shared__ float w2s[HO*64];
    __shared__ float h1s[K_*HO];
    __shared__ float redA[256], redB[256];
    const int t = threadIdx.x;
    const int cy = blockIdx.y;
    for (int e = t; e < HO*64; e += 256) {
        int c = e >> 6, cl = e & 63;
        w2s[e] = w2[c*HO + cy*64 + cl];
    }
    const int cA = t % HO;
    const float ac = st1[3*HO + cA] * g1[cA];
    const float bc = be1[cA] - st1[2*HO + cA] * ac;
    const int c2l = t & 63, jh = t >> 6;
    const float b2v = b2[cy*64 + c2l];
    float ssum = 0.f, ssq = 0.f;
    for (int p = blockIdx.x; p < BN_; p += gridDim.x) {
        __syncthreads();
        const int bbase = p & ~(N_-1);
        const float Pv = P[p*HO + cA];
        for (int e = t; e < K_*HO; e += 256) {
            int j = e / HO;
            int m = idx[p*K_ + j];
            float z = Pv + Q[(bbase + m)*HO + cA];
            h1s[e] = fmaxf(z*ac + bc, 0.f);
        }
        __syncthreads();
        float acc[5];
        #pragma unroll
        for (int q = 0; q < 5; ++q) acc[q] = b2v;
        for (int c = 0; c < HO; ++c) {
            float wv = w2s[c*64 + c2l];
            #pragma unroll
            for (int q = 0; q < 5; ++q)
                acc[q] += h1s[(jh + q*4)*HO + c] * wv;
        }
        float mx = acc[0], mn = acc[0];
        #pragma unroll
        for (int q = 0; q < 5; ++q) {
            mx = fmaxf(mx, acc[q]); mn = fminf(mn, acc[q]);
            ssum += acc[q]; ssq += acc[q]*acc[q];
        }
        redA[t] = mx; redB[t] = mn;
        __syncthreads();
        if (t < 64) {
            float M = redA[t], Mn = redB[t];
            #pragma unroll
            for (int g = 1; g < 4; ++g) { M = fmaxf(M, redA[g*64 + t]); Mn = fminf(Mn, redB[g*64 + t]); }
            zmax[p*HO + cy*64 + t] = M;
            zmin[p*HO + cy*64 + t] = Mn;
        }
    }
    __syncthreads();
    redA[t] = ssum; redB[t] = ssq;
    __syncthreads();
    if (t < 64) {
        float s = redA[t], s2 = redB[t];
        #pragma unroll
        for (int g = 1; g < 4; ++g) { s += redA[g*64 + t]; s2 += redB[g*64 + t]; }
        atomicAdd(&stOut[cy*64 + t], s);
        atomicAdd(&stOut[HO + cy*64 + t], s2);
    }
}

template<int HO>
__global__ __launch_bounds__(256) void conv_fin_kernel(
    const float* __restrict__ zmax, const float* __restrict__ zmin,
    const float* __restrict__ st2, const float* __restrict__ g2, const float* __restrict__ be2,
    float* __restrict__ out)
{
    int e = blockIdx.x*256 + threadIdx.x;
    int c = e & (HO-1);
    float g = g2[c];
    float a = st2[3*HO + c] * g;
    float sel = (g >= 0.f) ? zmax[e] : zmin[e];
    out[e] = fmaxf((sel - st2[2*HO + c]) * a + be2[c], 0.f);
}

// ---------------------------------------------------------------- classifier
__global__ __launch_bounds__(256) void cls1_kernel(
    const float* __restrict__ x1, const float* __restrict__ x2f,
    const float* __restrict__ W, const float* __restrict__ b1,
    float* __restrict__ z, float* __restrict__ stOut)
{
    __shared__ float ws[192*64];
    __shared__ float xr[4*192];
    __shared__ float red[256], red2[256];
    const int t = threadIdx.x, cy = blockIdx.y;
    for (int e = t; e < 192*64; e += 256) {
        int c = e >> 6, cl = e & 63;
        ws[e] = W[c*128 + cy*64 + cl];
    }
    const int pl = t >> 6, c2l = t & 63;
    const float b1v = b1[cy*64 + c2l];
    float ssum = 0.f, ssq = 0.f;
    for (int p0 = blockIdx.x*4; p0 < BN_; p0 += gridDim.x*4) {
        __syncthreads();
        for (int l = t; l < 4*192; l += 256) {
            int pp = l / 192, cc = l % 192;
            xr[l] = (cc < 64) ? x1[(p0+pp)*64 + cc] : x2f[(p0+pp)*128 + cc - 64];
        }
        __syncthreads();
        float acc = b1v;
        const float* xx = xr + pl*192;
        #pragma unroll 8
        for (int c = 0; c < 192; ++c) acc += xx[c] * ws[c*64 + c2l];
        z[(p0+pl)*128 + cy*64 + c2l] = acc;
        ssum += acc; ssq += acc*acc;
    }
    __syncthreads();
    red[t] = ssum; red2[t] = ssq;
    __syncthreads();
    if (t < 64) {
        float s = red[t], s2 = red2[t];
        #pragma unroll
        for (int g = 1; g < 4; ++g) { s += red[g*64 + t]; s2 += red2[g*64 + t]; }
        atomicAdd(&stOut[cy*64 + t], s);
        atomicAdd(&stOut[128 + cy*64 + t], s2);
    }
}

__global__ __launch_bounds__(256) void cls_fin_kernel(
    const float* __restrict__ z, const float* __restrict__ st,
    const float* __restrict__ g, const float* __restrict__ be,
    const float* __restrict__ w2, const float* __restrict__ b2,
    float* __restrict__ out)
{
    const int t = threadIdx.x, w = t >> 6, L = t & 63;
    const int p = blockIdx.x*4 + w;
    float s = 0.f;
    #pragma unroll
    for (int h = 0; h < 2; ++h) {
        int c = L + h*64;
        float v = (z[p*128 + c] - st[256 + c]) * st[384 + c] * g[c] + be[c];
        s += fmaxf(v, 0.f) * w2[c];
    }
    #pragma unroll
    for (int off = 32; off; off >>= 1) s += __shfl_xor(s, off);
    if (L == 0) out[p] = s + b2[0];
}

// ---------------------------------------------------------------- launch
extern "C" void kernel_launch(void* const* d_in, const int* in_sizes, int n_in,
                              void* d_out, int out_size, void* d_ws, size_t ws_size,
                              hipStream_t stream)
{
    const float* x      = (const float*)d_in[0];
    const float* c1_w1  = (const float*)d_in[1];
    const float* c1_b1  = (const float*)d_in[2];
    const float* c1_g1  = (const float*)d_in[3];
    const float* c1_be1 = (const float*)d_in[4];
    const float* c1_w2  = (const float*)d_in[5];
    const float* c1_b2  = (const float*)d_in[6];
    const float* c1_g2  = (const float*)d_in[7];
    const float* c1_be2 = (const float*)d_in[8];
    const float* c2_w1  = (const float*)d_in[9];
    const float* c2_b1  = (const float*)d_in[10];
    const float* c2_g1  = (const float*)d_in[11];
    const float* c2_be1 = (const float*)d_in[12];
    const float* c2_w2  = (const float*)d_in[13];
    const float* c2_b2  = (const float*)d_in[14];
    const float* c2_g2  = (const float*)d_in[15];
    const float* c2_be2 = (const float*)d_in[16];
    const float* cls_w1 = (const float*)d_in[17];
    const float* cls_b1 = (const float*)d_in[18];
    const float* cls_g1 = (const float*)d_in[19];
    const float* cls_be1= (const float*)d_in[20];
    const float* cls_w2 = (const float*)d_in[21];
    const float* cls_b2 = (const float*)d_in[22];
    (void)in_sizes; (void)n_in; (void)out_size; (void)ws_size;

    char* ws = (char*)d_ws;
    size_t off = 0;
    auto alloc = [&](size_t bytes) { char* p = ws + off; off += (bytes + 255) & ~255ull; return p; };
    float* A    = (float*)alloc((size_t)16<<20);   // P1 -> P2 -> zcls
    float* Bq   = (float*)alloc((size_t)16<<20);   // Q1 -> Q2
    float* zmax = (float*)alloc((size_t)16<<20);   // also hosts Xh/Xl between conv1 and conv2
    float* zmin = (float*)alloc((size_t)16<<20);
    float* x1b  = (float*)alloc((size_t)8<<20);
    float* x2b  = (float*)alloc((size_t)16<<20);   // also hosts idx24 during kNN2 phase
    int*   idx  = (int*)  alloc((size_t)BN_*K_*4); // idx1 -> idx2
    float* nrm  = (float*)alloc((size_t)BN_*4);
    float* st   = (float*)alloc((size_t)5*512*4);
    float *st0 = st, *st1 = st+512, *st2 = st+1024, *st3 = st+1536, *st4 = st+2048;

    // split-bf16 feature buffers alias zmax (dead between conv_fin<64> and conv_l2<128>)
    unsigned short* Xh = (unsigned short*)zmax;                       // 4 MB
    unsigned short* Xl = (unsigned short*)((char*)zmax + (4<<20));    // 4 MB
    // approx top-KS_ indices alias x2b (dead until conv_fin<128>)
    int* idx24 = (int*)x2b;                                           // 3.7 MB

    zero_kernel<<<1, 256, 0, stream>>>(st, 5*512);

    // ---- EdgeConv 1
    knn4_kernel<<<dim3(N_/16, B_), 1024, 0, stream>>>(x, idx);
    pq1_kernel<<<BN_/4, 256, 0, stream>>>(x, c1_w1, c1_b1, A, Bq);
    stats_l1_kernel<64><<<2048, 256, 0, stream>>>(A, Bq, idx, st0);
    finalize_kernel<<<1, 128, 0, stream>>>(st0, 64, 1.f/655360.f);
    conv_l2_kernel<64><<<dim3(2048,1), 256, 0, stream>>>(A, Bq, idx, st0, c1_g1, c1_be1, c1_w2, c1_b2, zmax, zmin, st1);
    finalize_kernel<<<1, 128, 0, stream>>>(st1, 64, 1.f/655360.f);
    conv_fin_kernel<64><<<BN_*64/256, 256, 0, stream>>>(zmax, zmin, st1, c1_g2, c1_be2, x1b);

    // ---- EdgeConv 2
    prep64_kernel<<<BN_/4, 256, 0, stream>>>(x1b, Xh, Xl, nrm);
    knn64v4_kernel<<<dim3(N_/16, B_), 1024, 0, stream>>>(Xh, Xl, nrm, idx24);
    rescore_kernel<<<BN_/4, 256, 0, stream>>>(x1b, nrm, idx24, idx);
    pq2_kernel<<<1024, 256, 0, stream>>>(x1b, c2_w1, c2_b1, A, Bq);
    stats_l1_kernel<128><<<2048, 256, 0, stream>>>(A, Bq, idx, st2);
    finalize_kernel<<<1, 128, 0, stream>>>(st2, 128, 1.f/655360.f);
    conv_l2_kernel<128><<<dim3(2048,2), 256, 0, stream>>>(A, Bq, idx, st2, c2_g1, c2_be1, c2_w2, c2_b2, zmax, zmin, st3);
    finalize_kernel<<<1, 128, 0, stream>>>(st3, 128, 1.f/655360.f);
    conv_fin_kernel<128><<<BN_*128/256, 256, 0, stream>>>(zmax, zmin, st3, c2_g2, c2_be2, x2b);

    // ---- classifier
    cls1_kernel<<<dim3(512,2), 256, 0, stream>>>(x1b, x2b, cls_w1, cls_b1, A, st4);
    finalize_kernel<<<1, 128, 0, stream>>>(st4, 128, 1.f/32768.f);
    cls_fin_kernel<<<BN_/4, 256, 0, stream>>>(A, st4, cls_g1, cls_be1, cls_w2, cls_b2, (float*)d_out);
}

// Round 7
// 1821.494 us; speedup vs baseline: 1.6993x; 1.3435x over previous
//
#include <hip/hip_runtime.h>
#include <math.h>

#define B_ 8
#define N_ 4096
#define K_ 20
#define KS_ 28          // approx-select width; exact rescore trims to K_
#define BN_ (B_*N_)

typedef __attribute__((ext_vector_type(8))) short bf16x8;
typedef __attribute__((ext_vector_type(4))) float f32x4;

// ---------------------------------------------------------------- utilities
__global__ void zero_kernel(float* p, int n)
{
    for (int e = threadIdx.x; e < n; e += 256) p[e] = 0.f;
}

// mean/rstd from accumulated sum/sumsq.  layout: [sum(H), sumsq(H), mean(H), rstd(H)]
__global__ void finalize_kernel(float* st, int H, float invCount)
{
    int t = threadIdx.x;
    if (t < H) {
        float mean = st[t] * invCount;
        float var  = fmaxf(st[H + t] * invCount - mean * mean, 0.f);
        st[2*H + t] = mean;
        st[3*H + t] = 1.f / sqrtf(var + 1e-5f);
    }
}

// ---------------------------------------------------------------- kNN, C=4
__global__ __launch_bounds__(1024) void knn4_kernel(const float* __restrict__ x, int* __restrict__ idxout)
{
    __shared__ float4 xt[N_];
    const int b = blockIdx.y;
    const int t = threadIdx.x;
    const float4* xg = (const float4*)x + b*N_;
    for (int e = t; e < N_; e += 1024) xt[e] = xg[e];
    __syncthreads();
    const int w = t >> 6, L = t & 63;
    const int n = blockIdx.x*16 + w;
    const float4 q = xt[n];
    float d[64];
    #pragma unroll
    for (int s = 0; s < 64; ++s) {
        float4 v = xt[(s<<6) | L];
        float nn = v.x*v.x + v.y*v.y + v.z*v.z + v.w*v.w;
        float dp = q.x*v.x + q.y*v.y + q.z*v.z + q.w*v.w;
        d[s] = nn - 2.f*dp;   // |xn|^2 dropped: rank-equivalent
    }
    const float MX = 3.4e38f;
    float m1 = MX, m2 = MX; int i1 = 0, i2 = 0;
    #pragma unroll
    for (int j = 0; j < 64; ++j) {
        float v = d[j];
        bool c1 = v < m1, c2 = v < m2;
        m2 = c1 ? m1 : (c2 ? v : m2);
        i2 = c1 ? i1 : (c2 ? j : i2);
        m1 = c1 ? v : m1;
        i1 = c1 ? j : i1;
    }
    bool have2 = true;
    unsigned long long used = 0;
    int mywin = 0;
    for (int r = 0; r < K_; ++r) {
        float bv = m1; int bg = (i1<<6) | L;
        #pragma unroll
        for (int off = 32; off; off >>= 1) {
            float ov = __shfl_xor(bv, off);
            int   og = __shfl_xor(bg, off);
            bool tk = (ov < bv) || (ov == bv && og < bg);
            bv = tk ? ov : bv; bg = tk ? og : bg;
        }
        if (L == r) mywin = bg;
        if (L == (bg & 63)) {
            used |= 1ull << i1;
            if (have2) { m1 = m2; i1 = i2; have2 = false; }
            else {
                m1 = MX; m2 = MX; i1 = 0; i2 = 0;
                #pragma unroll
                for (int j = 0; j < 64; ++j) {
                    float v = ((used >> j) & 1ull) ? MX : d[j];
                    bool c1 = v < m1, c2 = v < m2;
                    m2 = c1 ? m1 : (c2 ? v : m2);
                    i2 = c1 ? i1 : (c2 ? j : i2);
                    m1 = c1 ? v : m1;
                    i1 = c1 ? j : i1;
                }
                have2 = true;
            }
        }
    }
    if (L < K_) idxout[(b*N_ + n)*K_ + L] = mywin;
}

// ---------------------------------------------------------------- fp32 -> bf16 RNE
static __device__ inline unsigned short f2bf(float f)
{
    unsigned u = __float_as_uint(f);
    unsigned r = (u + 0x7fffu + ((u >> 16) & 1u)) >> 16;   // RNE
    return (unsigned short)r;
}

__global__ __launch_bounds__(256) void prep64_kernel(const float* __restrict__ x,
                                                     unsigned short* __restrict__ Xh,
                                                     unsigned short* __restrict__ Xl,
                                                     float* __restrict__ nrm)
{
    const int t = threadIdx.x, L = t & 63;
    const int row = blockIdx.x*4 + (t >> 6);
    const float v = x[row*64 + L];
    unsigned short h = f2bf(v);
    float hf = __uint_as_float((unsigned)h << 16);
    unsigned short l = f2bf(v - hf);
    Xh[row*64 + L] = h;
    Xl[row*64 + L] = l;
    float s = v * v;
    #pragma unroll
    for (int off = 32; off; off >>= 1) s += __shfl_xor(s, off);
    if (L == 0) nrm[row] = s;
}

// ---------------------------------------------------------------- kNN, C=64 via MFMA (split-bf16 Gram, approx)
// v4 (R5-validated): 16 waves = 16 distinct queries; per 1024-chunk each wave
// MFMAs its 64-candidate slice into the 16x1024 LDS tile, then reads back its
// own row; single register-resident top-KS_ selection per wave.
__global__ __launch_bounds__(1024, 4) void knn64v4_kernel(
    const unsigned short* __restrict__ Xh, const unsigned short* __restrict__ Xl,
    const float* __restrict__ nrm, int* __restrict__ idx24)
{
    __shared__ float dist[16*1024];   // exactly 64 KB
    const int b = blockIdx.y, t = threadIdx.x;
    const int w = t >> 6, L = t & 63;
    const int q0 = blockIdx.x * 16;
    const int m = L & 15, kq = (L >> 4) * 8;
    const size_t rowbase = (size_t)b * N_ * 64;

    const unsigned short* aph = Xh + rowbase + (size_t)(q0 + m)*64 + kq;
    const unsigned short* apl = Xl + rowbase + (size_t)(q0 + m)*64 + kq;
    const bf16x8 a_h0 = *(const bf16x8*)(aph);
    const bf16x8 a_h1 = *(const bf16x8*)(aph + 32);
    const bf16x8 a_l0 = *(const bf16x8*)(apl);
    const bf16x8 a_l1 = *(const bf16x8*)(apl + 32);

    float d[64];
    #pragma unroll
    for (int ck = 0; ck < 4; ++ck) {
        const int cq = ck * 1024;
        __syncthreads();
        for (int tt = 0; tt < 4; ++tt) {
            const int cbase = w*64 + tt*16;
            const unsigned short* bph = Xh + rowbase + (size_t)(cq + cbase + m)*64 + kq;
            const unsigned short* bpl = Xl + rowbase + (size_t)(cq + cbase + m)*64 + kq;
            bf16x8 b_h0 = *(const bf16x8*)(bph);
            bf16x8 b_h1 = *(const bf16x8*)(bph + 32);
            bf16x8 b_l0 = *(const bf16x8*)(bpl);
            bf16x8 b_l1 = *(const bf16x8*)(bpl + 32);
            f32x4 acc = {0.f, 0.f, 0.f, 0.f};
            acc = __builtin_amdgcn_mfma_f32_16x16x32_bf16(a_h0, b_h0, acc, 0, 0, 0);
            acc = __builtin_amdgcn_mfma_f32_16x16x32_bf16(a_h1, b_h1, acc, 0, 0, 0);
            acc = __builtin_amdgcn_mfma_f32_16x16x32_bf16(a_l0, b_h0, acc, 0, 0, 0);
            acc = __builtin_amdgcn_mfma_f32_16x16x32_bf16(a_l1, b_h1, acc, 0, 0, 0);
            acc = __builtin_amdgcn_mfma_f32_16x16x32_bf16(a_h0, b_l0, acc, 0, 0, 0);
            acc = __builtin_amdgcn_mfma_f32_16x16x32_bf16(a_h1, b_l1, acc, 0, 0, 0);
            const float nv = nrm[b*N_ + cq + cbase + m];
            #pragma unroll
            for (int r = 0; r < 4; ++r) {
                const int qrow = (L >> 4)*4 + r;   // C/D: row=(lane>>4)*4+reg
                dist[qrow*1024 + cbase + m] = nv - 2.f*acc[r];
            }
        }
        __syncthreads();
        #pragma unroll
        for (int s = 0; s < 16; ++s)
            d[ck*16 + s] = dist[w*1024 + (s<<6) + L];
    }

    const float MX = 3.4e38f;
    float m1 = MX, m2 = MX; int i1 = 0, i2 = 0;
    #pragma unroll
    for (int j = 0; j < 64; ++j) {
        float v = d[j];
        bool c1 = v < m1, c2 = v < m2;
        m2 = c1 ? m1 : (c2 ? v : m2);
        i2 = c1 ? i1 : (c2 ? j : i2);
        m1 = c1 ? v : m1;
        i1 = c1 ? j : i1;
    }
    bool have2 = true;
    unsigned long long used = 0;
    int mywin = 0;
    for (int r = 0; r < KS_; ++r) {
        float bv = m1; int bg = (i1<<6) | L;
        #pragma unroll
        for (int off = 32; off; off >>= 1) {
            float ov = __shfl_xor(bv, off);
            int   og = __shfl_xor(bg, off);
            bool tk = (ov < bv) || (ov == bv && og < bg);
            bv = tk ? ov : bv; bg = tk ? og : bg;
        }
        if (L == r) mywin = bg;
        if (L == (bg & 63)) {
            used |= 1ull << i1;
            if (have2) { m1 = m2; i1 = i2; have2 = false; }
            else {
                m1 = MX; m2 = MX; i1 = 0; i2 = 0;
                #pragma unroll
                for (int j = 0; j < 64; ++j) {
                    float v = ((used >> j) & 1ull) ? MX : d[j];
                    bool c1 = v < m1, c2 = v < m2;
                    m2 = c1 ? m1 : (c2 ? v : m2);
                    i2 = c1 ? i1 : (c2 ? j : i2);
                    m1 = c1 ? v : m1;
                    i1 = c1 ? j : i1;
                }
                have2 = true;
            }
        }
    }
    if (L < KS_) idx24[((size_t)b*N_ + q0 + w)*KS_ + L] = mywin;
}

// ---------------------------------------------------------------- exact fp32 rescore of the KS_ candidates
__global__ __launch_bounds__(256) void rescore_kernel(const float* __restrict__ x1, const float* __restrict__ nrm,
                                                      const int* __restrict__ idx24, int* __restrict__ idxout)
{
    const int t = threadIdx.x, w = t >> 6, L = t & 63;
    const int p = blockIdx.x*4 + w;
    const int bbase = p & ~(N_-1);
    const float MX = 3.4e38f;
    float dv = MX; int di = 0x7fffffff;
    if (L < KS_) {
        const int ci = idx24[(size_t)p*KS_ + L];
        const float4* qr = (const float4*)(x1 + (size_t)p*64);
        const float4* cr = (const float4*)(x1 + (size_t)(bbase + ci)*64);
        float dot = 0.f;
        #pragma unroll
        for (int i = 0; i < 16; ++i) {
            float4 a = qr[i], bx = cr[i];
            dot += a.x*bx.x + a.y*bx.y + a.z*bx.z + a.w*bx.w;
        }
        dv = nrm[bbase + ci] - 2.f*dot;
        di = ci;
    }
    int myfin = 0;
    for (int r = 0; r < K_; ++r) {
        float bv = dv; int bg = di;
        #pragma unroll
        for (int off = 32; off; off >>= 1) {
            float ov = __shfl_xor(bv, off);
            int   og = __shfl_xor(bg, off);
            bool tk = (ov < bv) || (ov == bv && og < bg);
            bv = tk ? ov : bv; bg = tk ? og : bg;
        }
        if (L == r) myfin = bg;
        if (di == bg) dv = MX;
    }
    if (L < K_) idxout[(size_t)p*K_ + L] = myfin;
}

// ---------------------------------------------------------------- P/Q precompute
__global__ __launch_bounds__(256) void pq1_kernel(const float* __restrict__ x, const float* __restrict__ W,
                                                  const float* __restrict__ b1,
                                                  float* __restrict__ P, float* __restrict__ Q)
{
    __shared__ float wd[256], wb[256];
    const int t = threadIdx.x;
    wd[t] = W[t] - W[256 + t];
    wb[t] = W[256 + t];
    __syncthreads();
    const int p = blockIdx.x*4 + (t >> 6), c = t & 63;
    const float4 xv = ((const float4*)x)[p];
    float Pv = b1[c] + xv.x*wd[c] + xv.y*wd[64+c] + xv.z*wd[128+c] + xv.w*wd[192+c];
    float Qv =         xv.x*wb[c] + xv.y*wb[64+c] + xv.z*wb[128+c] + xv.w*wb[192+c];
    P[p*64 + c] = Pv;
    Q[p*64 + c] = Qv;
}

__global__ __launch_bounds__(256) void pq2_kernel(const float* __restrict__ x1, const float* __restrict__ W,
                                                  const float* __restrict__ b1,
                                                  float* __restrict__ P, float* __restrict__ Q)
{
    __shared__ float wd[64*128], wb[64*128];
    const int t = threadIdx.x;
    for (int e = t; e < 8192; e += 256) {
        float wt = W[e], wbo = W[8192 + e];
        wd[e] = wt - wbo; wb[e] = wbo;
    }
    __syncthreads();
    const int pl = t >> 7, c = t & 127;
    const float b1v = b1[c];
    for (int p0 = blockIdx.x*2; p0 < BN_; p0 += gridDim.x*2) {
        const int p = p0 + pl;
        float Pv = b1v, Qv = 0.f;
        const float* xrow = x1 + p*64;
        #pragma unroll 8
        for (int k = 0; k < 64; ++k) {
            float xv = xrow[k];
            Pv += xv * wd[k*128 + c];
            Qv += xv * wb[k*128 + c];
        }
        P[p*128 + c] = Pv;
        Q[p*128 + c] = Qv;
    }
}

// ---------------------------------------------------------------- layer-1 BN stats
template<int HO>
__global__ __launch_bounds__(256) void stats_l1_kernel(const float* __restrict__ P, const float* __restrict__ Q,
                                                       const int* __restrict__ idx, float* __restrict__ stOut)
{
    constexpr int G = 256/HO;
    __shared__ float red[256], red2[256];
    const int t = threadIdx.x, c = t % HO, g = t / HO;
    float s = 0.f, s2 = 0.f;
    for (int p = blockIdx.x; p < BN_; p += gridDim.x) {
        const float Pv = P[p*HO + c];
        const int bbase = p & ~(N_-1);
        for (int j = g; j < K_; j += G) {
            int m = idx[p*K_ + j];
            float z = Pv + Q[(bbase + m)*HO + c];
            s += z; s2 += z*z;
        }
    }
    red[t] = s; red2[t] = s2;
    __syncthreads();
    if (t < HO) {
        float a = red[t], a2 = red2[t];
        #pragma unroll
        for (int q = 1; q < G; ++q) { a += red[q*HO + t]; a2 += red2[q*HO + t]; }
        atomicAdd(&stOut[t], a);
        atomicAdd(&stOut[HO + t], a2);
    }
}

// ---------------------------------------------------------------- EdgeConv layer-2, exact fp32 (used for conv1:
// its output feeds kNN2, which is flip-sensitive to ~1e-4 feature perturbation)
template<int HO>
__global__ __launch_bounds__(256) void conv_l2_kernel(
    const float* __restrict__ P, const float* __restrict__ Q, const int* __restrict__ idx,
    const float* __restrict__ st1, const float* __restrict__ g1, const float* __restrict__ be1,
    const float* __restrict__ w2, const float* __restrict__ b2,
    float* __restrict__ zmax, float* __restrict__ zmin, float* __restrict__ stOut)
{
    __shared__ float w2s[HO*64];
    __shared__ float h1s[K_*HO];
    __shared__ float redA[256], redB[256];
    const int t = threadIdx.x;
    const int cy = blockIdx.y;
    for (int e = t; e < HO*64; e += 256) {
        int c = e >> 6, cl = e & 63;
        w2s[e] = w2[c*HO + cy*64 + cl];
    }
    const int cA = t % HO;
    const float ac = st1[3*HO + cA] * g1[cA];
    const float bc = be1[cA] - st1[2*HO + cA] * ac;
    const int c2l = t & 63, jh = t >> 6;
    const float b2v = b2[cy*64 + c2l];
    float ssum = 0.f, ssq = 0.f;
    for (int p = blockIdx.x; p < BN_; p += gridDim.x) {
        __syncthreads();
        const int bbase = p & ~(N_-1);
        const float Pv = P[p*HO + cA];
        for (int e = t; e < K_*HO; e += 256) {
            int j = e / HO;
            int m = idx[p*K_ + j];
            float z = Pv + Q[(bbase + m)*HO + cA];
            h1s[e] = fmaxf(z*ac + bc, 0.f);
        }
        __syncthreads();
        float acc[5];
        #pragma unroll
        for (int q = 0; q < 5; ++q) acc[q] = b2v;
        for (int c = 0; c < HO; ++c) {
            float wv = w2s[c*64 + c2l];
            #pragma unroll
            for (int q = 0; q < 5; ++q)
                acc[q] += h1s[(jh + q*4)*HO + c] * wv;
        }
        float mx = acc[0], mn = acc[0];
        #pragma unroll
        for (int q = 0; q < 5; ++q) {
            mx = fmaxf(mx, acc[q]); mn = fminf(mn, acc[q]);
            ssum += acc[q]; ssq += acc[q]*acc[q];
        }
        redA[t] = mx; redB[t] = mn;
        __syncthreads();
        if (t < 64) {
            float M = redA[t], Mn = redB[t];
            #pragma unroll
            for (int g = 1; g < 4; ++g) { M = fmaxf(M, redA[g*64 + t]); Mn = fminf(Mn, redB[g*64 + t]); }
            zmax[p*HO + cy*64 + t] = M;
            zmin[p*HO + cy*64 + t] = Mn;
        }
    }
    __syncthreads();
    redA[t] = ssum; redB[t] = ssq;
    __syncthreads();
    if (t < 64) {
        float s = redA[t], s2 = redB[t];
        #pragma unroll
        for (int g = 1; g < 4; ++g) { s += redA[g*64 + t]; s2 += redB[g*64 + t]; }
        atomicAdd(&stOut[cy*64 + t], s);
        atomicAdd(&stOut[HO + cy*64 + t], s2);
    }
}

// ---------------------------------------------------------------- W2^T split-bf16 prep
__global__ __launch_bounds__(256) void prep_w2t_kernel(const float* __restrict__ W,
                                                       unsigned short* __restrict__ wh,
                                                       unsigned short* __restrict__ wl, int HO)
{
    const int e = blockIdx.x*256 + threadIdx.x;   // e = k*HO + c
    const int k = e / HO, c = e % HO;
    const float v = W[e];
    unsigned short h = f2bf(v);
    float hf = __uint_as_float((unsigned)h << 16);
    wh[c*HO + k] = h;
    wl[c*HO + k] = f2bf(v - hf);
}

// ---------------------------------------------------------------- EdgeConv layer-2 via MFMA (split-bf16)
// Used for conv2 only: output feeds the classifier (value-continuous, no
// downstream selection), so ~1e-3 bf16-split error is harmless.
template<int HO>
__global__ __launch_bounds__(256) void conv_l2_mfma_kernel(
    const float* __restrict__ P, const float* __restrict__ Q, const int* __restrict__ idx,
    const float* __restrict__ st1, const float* __restrict__ g1, const float* __restrict__ be1,
    const unsigned short* __restrict__ w2h, const unsigned short* __restrict__ w2l,
    const float* __restrict__ b2,
    float* __restrict__ zmax, float* __restrict__ zmin, float* __restrict__ stOut)
{
    constexpr int HOP = HO + 8;        // bf16 row stride (16B-aligned rows)
    constexpr int CDP = HO + 1;        // fp32 C-dump row stride
    constexpr int CTW = HO / 64;       // col-tiles per wave (4 waves)
    constexpr int KSn = HO / 32;       // K-steps
    constexpr int HSH = (HO == 128) ? 7 : 6;
    __shared__ __align__(16) short hs[2*80*HOP];
    __shared__ int sidx[80];
    float* cd = (float*)hs;

    const int t = threadIdx.x, w = t >> 6, L = t & 63;
    const int m16 = L & 15, q4 = L >> 4;

    const int kT = t & (HO - 1);
    const float ac = st1[3*HO + kT] * g1[kT];
    const float bc = be1[kT] - st1[2*HO + kT] * ac;

    bf16x8 Bh[CTW][KSn], Bl[CTW][KSn];
    #pragma unroll
    for (int ctl = 0; ctl < CTW; ++ctl)
        #pragma unroll
        for (int ks = 0; ks < KSn; ++ks) {
            const int c  = w*16*CTW + ctl*16 + m16;
            const int k0 = ks*32 + q4*8;
            Bh[ctl][ks] = *(const bf16x8*)(w2h + c*HO + k0);
            Bl[ctl][ks] = *(const bf16x8*)(w2l + c*HO + k0);
        }

    const float b2c = (t < HO) ? b2[t] : 0.f;
    float ssum = 0.f, ssq = 0.f;

    for (int p0 = blockIdx.x*4; p0 < BN_; p0 += gridDim.x*4) {
        const int bbase = p0 & ~(N_-1);
        __syncthreads();
        if (t < 80) sidx[t] = idx[p0*K_ + t];
        __syncthreads();
        for (int e = t; e < 80*HO; e += 256) {
            const int r  = e >> HSH;
            const int pl = (r*3277) >> 16;     // r/20 for r<80
            const int mI = sidx[r];
            float z = P[(size_t)(p0+pl)*HO + kT] + Q[(size_t)(bbase+mI)*HO + kT];
            float h = fmaxf(z*ac + bc, 0.f);
            unsigned short hh = f2bf(h);
            float hf = __uint_as_float((unsigned)hh << 16);
            unsigned short hl = f2bf(h - hf);
            hs[r*HOP + kT] = (short)hh;
            hs[80*HOP + r*HOP + kT] = (short)hl;
        }
        __syncthreads();
        f32x4 acc[5][CTW];
        #pragma unroll
        for (int rt = 0; rt < 5; ++rt)
            #pragma unroll
            for (int ctl = 0; ctl < CTW; ++ctl)
                acc[rt][ctl] = (f32x4){0.f, 0.f, 0.f, 0.f};
        #pragma unroll
        for (int rt = 0; rt < 5; ++rt)
            #pragma unroll
            for (int ks = 0; ks < KSn; ++ks) {
                const short* ap = hs + (rt*16 + m16)*HOP + ks*32 + q4*8;
                bf16x8 Ah = *(const bf16x8*)ap;
                bf16x8 Al = *(const bf16x8*)(ap + 80*HOP);
                #pragma unroll
                for (int ctl = 0; ctl < CTW; ++ctl) {
                    acc[rt][ctl] = __builtin_amdgcn_mfma_f32_16x16x32_bf16(Ah, Bh[ctl][ks], acc[rt][ctl], 0, 0, 0);
                    acc[rt][ctl] = __builtin_amdgcn_mfma_f32_16x16x32_bf16(Al, Bh[ctl][ks], acc[rt][ctl], 0, 0, 0);
                    acc[rt][ctl] = __builtin_amdgcn_mfma_f32_16x16x32_bf16(Ah, Bl[ctl][ks], acc[rt][ctl], 0, 0, 0);
                }
            }
        __syncthreads();
        #pragma unroll
        for (int rt = 0; rt < 5; ++rt)
            #pragma unroll
            for (int ctl = 0; ctl < CTW; ++ctl) {
                const int col = w*16*CTW + ctl*16 + m16;
                #pragma unroll
                for (int ri = 0; ri < 4; ++ri) {
                    const int row = rt*16 + q4*4 + ri;
                    cd[row*CDP + col] = acc[rt][ctl][ri];
                }
            }
        __syncthreads();
        if (t < HO) {
            #pragma unroll
            for (int pl = 0; pl < 4; ++pl) {
                float mx = -3.4e38f, mn = 3.4e38f;
                #pragma unroll
                for (int j = 0; j < K_; ++j) {
                    float v = cd[(pl*20 + j)*CDP + t] + b2c;
                    mx = fmaxf(mx, v); mn = fminf(mn, v);
                    ssum += v; ssq += v*v;
                }
                zmax[(size_t)(p0+pl)*HO + t] = mx;
                zmin[(size_t)(p0+pl)*HO + t] = mn;
            }
        }
    }
    if (t < HO) {
        atomicAdd(&stOut[t], ssum);
        atomicAdd(&stOut[HO + t], ssq);
    }
}

// max_j relu(BN(z)) = relu(BN(max_j z)) for gamma>=0, min for gamma<0
template<int HO>
__global__ __launch_bounds__(256) void conv_fin_kernel(
    const float* __restrict__ zmax, const float* __restrict__ zmin,
    const float* __restrict__ st2, const float* __restrict__ g2, const float* __restrict__ be2,
    float* __restrict__ out)
{
    int e = blockIdx.x*256 + threadIdx.x;
    int c = e & (HO-1);
    float g = g2[c];
    float a = st2[3*HO + c] * g;
    float sel = (g >= 0.f) ? zmax[e] : zmin[e];
    out[e] = fmaxf((sel - st2[2*HO + c]) * a + be2[c], 0.f);
}

// ---------------------------------------------------------------- classifier
__global__ __launch_bounds__(256) void cls1_kernel(
    const float* __restrict__ x1, const float* __restrict__ x2f,
    const float* __restrict__ W, const float* __restrict__ b1,
    float* __restrict__ z, float* __restrict__ stOut)
{
    __shared__ float ws[192*64];
    __shared__ float xr[4*192];
    __shared__ float red[256], red2[256];
    const int t = threadIdx.x, cy = blockIdx.y;
    for (int e = t; e < 192*64; e += 256) {
        int c = e >> 6, cl = e & 63;
        ws[e] = W[c*128 + cy*64 + cl];
    }
    const int pl = t >> 6, c2l = t & 63;
    const float b1v = b1[cy*64 + c2l];
    float ssum = 0.f, ssq = 0.f;
    for (int p0 = blockIdx.x*4; p0 < BN_; p0 += gridDim.x*4) {
        __syncthreads();
        for (int l = t; l < 4*192; l += 256) {
            int pp = l / 192, cc = l % 192;
            xr[l] = (cc < 64) ? x1[(p0+pp)*64 + cc] : x2f[(p0+pp)*128 + cc - 64];
        }
        __syncthreads();
        float acc = b1v;
        const float* xx = xr + pl*192;
        #pragma unroll 8
        for (int c = 0; c < 192; ++c) acc += xx[c] * ws[c*64 + c2l];
        z[(p0+pl)*128 + cy*64 + c2l] = acc;
        ssum += acc; ssq += acc*acc;
    }
    __syncthreads();
    red[t] = ssum; red2[t] = ssq;
    __syncthreads();
    if (t < 64) {
        float s = red[t], s2 = red2[t];
        #pragma unroll
        for (int g = 1; g < 4; ++g) { s += red[g*64 + t]; s2 += red2[g*64 + t]; }
        atomicAdd(&stOut[cy*64 + t], s);
        atomicAdd(&stOut[128 + cy*64 + t], s2);
    }
}

__global__ __launch_bounds__(256) void cls_fin_kernel(
    const float* __restrict__ z, const float* __restrict__ st,
    const float* __restrict__ g, const float* __restrict__ be,
    const float* __restrict__ w2, const float* __restrict__ b2,
    float* __restrict__ out)
{
    const int t = threadIdx.x, w = t >> 6, L = t & 63;
    const int p = blockIdx.x*4 + w;
    float s = 0.f;
    #pragma unroll
    for (int h = 0; h < 2; ++h) {
        int c = L + h*64;
        float v = (z[p*128 + c] - st[256 + c]) * st[384 + c] * g[c] + be[c];
        s += fmaxf(v, 0.f) * w2[c];
    }
    #pragma unroll
    for (int off = 32; off; off >>= 1) s += __shfl_xor(s, off);
    if (L == 0) out[p] = s + b2[0];
}

// ---------------------------------------------------------------- launch
extern "C" void kernel_launch(void* const* d_in, const int* in_sizes, int n_in,
                              void* d_out, int out_size, void* d_ws, size_t ws_size,
                              hipStream_t stream)
{
    const float* x      = (const float*)d_in[0];
    const float* c1_w1  = (const float*)d_in[1];
    const float* c1_b1  = (const float*)d_in[2];
    const float* c1_g1  = (const float*)d_in[3];
    const float* c1_be1 = (const float*)d_in[4];
    const float* c1_w2  = (const float*)d_in[5];
    const float* c1_b2  = (const float*)d_in[6];
    const float* c1_g2  = (const float*)d_in[7];
    const float* c1_be2 = (const float*)d_in[8];
    const float* c2_w1  = (const float*)d_in[9];
    const float* c2_b1  = (const float*)d_in[10];
    const float* c2_g1  = (const float*)d_in[11];
    const float* c2_be1 = (const float*)d_in[12];
    const float* c2_w2  = (const float*)d_in[13];
    const float* c2_b2  = (const float*)d_in[14];
    const float* c2_g2  = (const float*)d_in[15];
    const float* c2_be2 = (const float*)d_in[16];
    const float* cls_w1 = (const float*)d_in[17];
    const float* cls_b1 = (const float*)d_in[18];
    const float* cls_g1 = (const float*)d_in[19];
    const float* cls_be1= (const float*)d_in[20];
    const float* cls_w2 = (const float*)d_in[21];
    const float* cls_b2 = (const float*)d_in[22];
    (void)in_sizes; (void)n_in; (void)out_size; (void)ws_size;

    char* ws = (char*)d_ws;
    size_t off = 0;
    auto alloc = [&](size_t bytes) { char* p = ws + off; off += (bytes + 255) & ~255ull; return p; };
    float* A    = (float*)alloc((size_t)16<<20);   // P1 -> P2 -> zcls
    float* Bq   = (float*)alloc((size_t)16<<20);   // Q1 -> Q2
    float* zmax = (float*)alloc((size_t)16<<20);   // also hosts Xh/Xl between conv1 and conv2
    float* zmin = (float*)alloc((size_t)16<<20);
    float* x1b  = (float*)alloc((size_t)8<<20);
    float* x2b  = (float*)alloc((size_t)16<<20);   // also hosts idx24 during kNN2 phase
    int*   idx  = (int*)  alloc((size_t)BN_*K_*4); // idx1 -> idx2
    float* nrm  = (float*)alloc((size_t)BN_*4);
    float* st   = (float*)alloc((size_t)5*512*4);
    unsigned short* w2th = (unsigned short*)alloc((size_t)128*128*2);  // W2^T hi
    unsigned short* w2tl = (unsigned short*)alloc((size_t)128*128*2);  // W2^T lo
    float *st0 = st, *st1 = st+512, *st2 = st+1024, *st3 = st+1536, *st4 = st+2048;

    // split-bf16 feature buffers alias zmax (dead between conv_fin<64> and conv_l2<128>)
    unsigned short* Xh = (unsigned short*)zmax;                       // 4 MB
    unsigned short* Xl = (unsigned short*)((char*)zmax + (4<<20));    // 4 MB
    // approx top-KS_ indices alias x2b (dead until conv_fin<128>)
    int* idx24 = (int*)x2b;

    zero_kernel<<<1, 256, 0, stream>>>(st, 5*512);

    // ---- EdgeConv 1 (exact fp32 conv: x1b feeds flip-sensitive kNN2)
    knn4_kernel<<<dim3(N_/16, B_), 1024, 0, stream>>>(x, idx);
    pq1_kernel<<<BN_/4, 256, 0, stream>>>(x, c1_w1, c1_b1, A, Bq);
    stats_l1_kernel<64><<<2048, 256, 0, stream>>>(A, Bq, idx, st0);
    finalize_kernel<<<1, 128, 0, stream>>>(st0, 64, 1.f/655360.f);
    conv_l2_kernel<64><<<dim3(2048,1), 256, 0, stream>>>(A, Bq, idx, st0, c1_g1, c1_be1, c1_w2, c1_b2, zmax, zmin, st1);
    finalize_kernel<<<1, 128, 0, stream>>>(st1, 64, 1.f/655360.f);
    conv_fin_kernel<64><<<BN_*64/256, 256, 0, stream>>>(zmax, zmin, st1, c1_g2, c1_be2, x1b);

    // ---- EdgeConv 2 (MFMA conv: x2b only feeds classifier)
    prep64_kernel<<<BN_/4, 256, 0, stream>>>(x1b, Xh, Xl, nrm);
    knn64v4_kernel<<<dim3(N_/16, B_), 1024, 0, stream>>>(Xh, Xl, nrm, idx24);
    rescore_kernel<<<BN_/4, 256, 0, stream>>>(x1b, nrm, idx24, idx);
    pq2_kernel<<<1024, 256, 0, stream>>>(x1b, c2_w1, c2_b1, A, Bq);
    stats_l1_kernel<128><<<2048, 256, 0, stream>>>(A, Bq, idx, st2);
    finalize_kernel<<<1, 128, 0, stream>>>(st2, 128, 1.f/655360.f);
    prep_w2t_kernel<<<128*128/256, 256, 0, stream>>>(c2_w2, w2th, w2tl, 128);
    conv_l2_mfma_kernel<128><<<2048, 256, 0, stream>>>(A, Bq, idx, st2, c2_g1, c2_be1, w2th, w2tl, c2_b2, zmax, zmin, st3);
    finalize_kernel<<<1, 128, 0, stream>>>(st3, 128, 1.f/655360.f);
    conv_fin_kernel<128><<<BN_*128/256, 256, 0, stream>>>(zmax, zmin, st3, c2_g2, c2_be2, x2b);

    // ---- classifier
    cls1_kernel<<<dim3(512,2), 256, 0, stream>>>(x1b, x2b, cls_w1, cls_b1, A, st4);
    finalize_kernel<<<1, 128, 0, stream>>>(st4, 128, 1.f/32768.f);
    cls_fin_kernel<<<BN_/4, 256, 0, stream>>>(A, st4, cls_g1, cls_be1, cls_w2, cls_b2, (float*)d_out);
}

// Round 10
// 1737.114 us; speedup vs baseline: 1.7819x; 1.0486x over previous
//
#include <hip/hip_runtime.h>
#include <math.h>

#define B_ 8
#define N_ 4096
#define K_ 20
#define KS_ 24          // approx-select width; exact rescore trims to K_ (R3-validated margin)
#define BN_ (B_*N_)

typedef __attribute__((ext_vector_type(8))) short bf16x8;
typedef __attribute__((ext_vector_type(4))) float f32x4;

// ---------------------------------------------------------------- utilities
__global__ void zero_kernel(float* p, int n)
{
    for (int e = threadIdx.x; e < n; e += 256) p[e] = 0.f;
}

// mean/rstd from accumulated sum/sumsq.  layout: [sum(H), sumsq(H), mean(H), rstd(H)]
__global__ void finalize_kernel(float* st, int H, float invCount)
{
    int t = threadIdx.x;
    if (t < H) {
        float mean = st[t] * invCount;
        float var  = fmaxf(st[H + t] * invCount - mean * mean, 0.f);
        st[2*H + t] = mean;
        st[3*H + t] = 1.f / sqrtf(var + 1e-5f);
    }
}

// ---------------------------------------------------------------- kNN, C=4
// R7-validated shuffle-butterfly selection (exact (value, candidate-index)
// lexicographic argmin — matches jax top_k tie-break).  DO NOT replace with
// DPP (R9: DPP reduce mis-selects on gfx950) or ballot (no rescore guard here).
__global__ __launch_bounds__(1024) void knn4_kernel(const float* __restrict__ x, int* __restrict__ idxout)
{
    __shared__ float4 xt[N_];
    const int b = blockIdx.y;
    const int t = threadIdx.x;
    const float4* xg = (const float4*)x + b*N_;
    for (int e = t; e < N_; e += 1024) xt[e] = xg[e];
    __syncthreads();
    const int w = t >> 6, L = t & 63;
    const int n = blockIdx.x*16 + w;
    const float4 q = xt[n];
    float d[64];
    #pragma unroll
    for (int s = 0; s < 64; ++s) {
        float4 v = xt[(s<<6) | L];
        float nn = v.x*v.x + v.y*v.y + v.z*v.z + v.w*v.w;
        float dp = q.x*v.x + q.y*v.y + q.z*v.z + q.w*v.w;
        d[s] = nn - 2.f*dp;   // |xn|^2 dropped: rank-equivalent
    }
    const float MX = 3.4e38f;
    float m1 = MX, m2 = MX; int i1 = 0, i2 = 0;
    #pragma unroll
    for (int j = 0; j < 64; ++j) {
        float v = d[j];
        bool c1 = v < m1, c2 = v < m2;
        m2 = c1 ? m1 : (c2 ? v : m2);
        i2 = c1 ? i1 : (c2 ? j : i2);
        m1 = c1 ? v : m1;
        i1 = c1 ? j : i1;
    }
    bool have2 = true;
    unsigned long long used = 0;
    int mywin = 0;
    for (int r = 0; r < K_; ++r) {
        float bv = m1; int bg = (i1<<6) | L;
        #pragma unroll
        for (int off = 32; off; off >>= 1) {
            float ov = __shfl_xor(bv, off);
            int   og = __shfl_xor(bg, off);
            bool tk = (ov < bv) || (ov == bv && og < bg);
            bv = tk ? ov : bv; bg = tk ? og : bg;
        }
        if (L == r) mywin = bg;
        if (L == (bg & 63)) {
            used |= 1ull << i1;
            if (have2) { m1 = m2; i1 = i2; have2 = false; }
            else {
                m1 = MX; m2 = MX; i1 = 0; i2 = 0;
                #pragma unroll
                for (int j = 0; j < 64; ++j) {
                    float v = ((used >> j) & 1ull) ? MX : d[j];
                    bool c1 = v < m1, c2 = v < m2;
                    m2 = c1 ? m1 : (c2 ? v : m2);
                    i2 = c1 ? i1 : (c2 ? j : i2);
                    m1 = c1 ? v : m1;
                    i1 = c1 ? j : i1;
                }
                have2 = true;
            }
        }
    }
    if (L < K_) idxout[(b*N_ + n)*K_ + L] = mywin;
}

// ---------------------------------------------------------------- fp32 -> bf16 RNE
static __device__ inline unsigned short f2bf(float f)
{
    unsigned u = __float_as_uint(f);
    unsigned r = (u + 0x7fffu + ((u >> 16) & 1u)) >> 16;   // RNE
    return (unsigned short)r;
}

__global__ __launch_bounds__(256) void prep64_kernel(const float* __restrict__ x,
                                                     unsigned short* __restrict__ Xh,
                                                     unsigned short* __restrict__ Xl,
                                                     float* __restrict__ nrm)
{
    const int t = threadIdx.x, L = t & 63;
    const int row = blockIdx.x*4 + (t >> 6);
    const float v = x[row*64 + L];
    unsigned short h = f2bf(v);
    float hf = __uint_as_float((unsigned)h << 16);
    unsigned short l = f2bf(v - hf);
    Xh[row*64 + L] = h;
    Xl[row*64 + L] = l;
    float s = v * v;
    #pragma unroll
    for (int off = 32; off; off >>= 1) s += __shfl_xor(s, off);
    if (L == 0) nrm[row] = s;
}

// ---------------------------------------------------------------- kNN, C=64 via MFMA (split-bf16 Gram, approx)
// v4 structure (R5/R7-validated).  Selection rounds: 6-shuffle value-only fmin
// butterfly + ballot + single readlane (7 LDS-pipe ops/round vs 12).  Tie-break
// is min-LANE instead of min-candidate — differs only under exact fp32 equality
// of two approx distances (measure-~0; pool order is re-established by the
// exact rescore, and the KS_-K_ margin covers boundary ties).
__global__ __launch_bounds__(1024, 4) void knn64v4_kernel(
    const unsigned short* __restrict__ Xh, const unsigned short* __restrict__ Xl,
    const float* __restrict__ nrm, int* __restrict__ idx24)
{
    __shared__ float dist[16*1024];   // exactly 64 KB
    const int b = blockIdx.y, t = threadIdx.x;
    const int w = t >> 6, L = t & 63;
    const int q0 = blockIdx.x * 16;
    const int m = L & 15, kq = (L >> 4) * 8;
    const size_t rowbase = (size_t)b * N_ * 64;

    const unsigned short* aph = Xh + rowbase + (size_t)(q0 + m)*64 + kq;
    const unsigned short* apl = Xl + rowbase + (size_t)(q0 + m)*64 + kq;
    const bf16x8 a_h0 = *(const bf16x8*)(aph);
    const bf16x8 a_h1 = *(const bf16x8*)(aph + 32);
    const bf16x8 a_l0 = *(const bf16x8*)(apl);
    const bf16x8 a_l1 = *(const bf16x8*)(apl + 32);

    float d[64];
    #pragma unroll
    for (int ck = 0; ck < 4; ++ck) {
        const int cq = ck * 1024;
        __syncthreads();
        for (int tt = 0; tt < 4; ++tt) {
            const int cbase = w*64 + tt*16;
            const unsigned short* bph = Xh + rowbase + (size_t)(cq + cbase + m)*64 + kq;
            const unsigned short* bpl = Xl + rowbase + (size_t)(cq + cbase + m)*64 + kq;
            bf16x8 b_h0 = *(const bf16x8*)(bph);
            bf16x8 b_h1 = *(const bf16x8*)(bph + 32);
            bf16x8 b_l0 = *(const bf16x8*)(bpl);
            bf16x8 b_l1 = *(const bf16x8*)(bpl + 32);
            f32x4 acc = {0.f, 0.f, 0.f, 0.f};
            acc = __builtin_amdgcn_mfma_f32_16x16x32_bf16(a_h0, b_h0, acc, 0, 0, 0);
            acc = __builtin_amdgcn_mfma_f32_16x16x32_bf16(a_h1, b_h1, acc, 0, 0, 0);
            acc = __builtin_amdgcn_mfma_f32_16x16x32_bf16(a_l0, b_h0, acc, 0, 0, 0);
            acc = __builtin_amdgcn_mfma_f32_16x16x32_bf16(a_l1, b_h1, acc, 0, 0, 0);
            acc = __builtin_amdgcn_mfma_f32_16x16x32_bf16(a_h0, b_l0, acc, 0, 0, 0);
            acc = __builtin_amdgcn_mfma_f32_16x16x32_bf16(a_h1, b_l1, acc, 0, 0, 0);
            const float nv = nrm[b*N_ + cq + cbase + m];
            #pragma unroll
            for (int r = 0; r < 4; ++r) {
                const int qrow = (L >> 4)*4 + r;   // C/D: row=(lane>>4)*4+reg
                dist[qrow*1024 + cbase + m] = nv - 2.f*acc[r];
            }
        }
        __syncthreads();
        #pragma unroll
        for (int s = 0; s < 16; ++s)
            d[ck*16 + s] = dist[w*1024 + (s<<6) + L];
    }

    const float MX = 3.4e38f;
    float m1 = MX, m2 = MX; int i1 = 0, i2 = 0;
    #pragma unroll
    for (int j = 0; j < 64; ++j) {
        float v = d[j];
        bool c1 = v < m1, c2 = v < m2;
        m2 = c1 ? m1 : (c2 ? v : m2);
        i2 = c1 ? i1 : (c2 ? j : i2);
        m1 = c1 ? v : m1;
        i1 = c1 ? j : i1;
    }
    bool have2 = true;
    unsigned long long used = 0;
    int mywin = 0;
    for (int r = 0; r < KS_; ++r) {
        float bmin = m1;
        #pragma unroll
        for (int off = 32; off; off >>= 1)
            bmin = fminf(bmin, __shfl_xor(bmin, off));
        const unsigned long long tied = __ballot(m1 == bmin);
        const int winlane = (int)__ffsll((unsigned long long)tied) - 1;
        const int wslot = __shfl(i1, winlane);
        if (L == r) mywin = (wslot << 6) | winlane;
        if (L == winlane) {
            used |= 1ull << i1;
            if (have2) { m1 = m2; i1 = i2; have2 = false; }
            else {
                m1 = MX; m2 = MX; i1 = 0; i2 = 0;
                #pragma unroll
                for (int j = 0; j < 64; ++j) {
                    float v = ((used >> j) & 1ull) ? MX : d[j];
                    bool c1 = v < m1, c2 = v < m2;
                    m2 = c1 ? m1 : (c2 ? v : m2);
                    i2 = c1 ? i1 : (c2 ? j : i2);
                    m1 = c1 ? v : m1;
                    i1 = c1 ? j : i1;
                }
                have2 = true;
            }
        }
    }
    if (L < KS_) idx24[((size_t)b*N_ + q0 + w)*KS_ + L] = mywin;
}

// ---------------------------------------------------------------- exact fp32 rescore of the KS_ candidates
// R7-validated butterfly (exact (value, candidate-index) order — defines the
// final, reference-matching tie-break).
__global__ __launch_bounds__(256) void rescore_kernel(const float* __restrict__ x1, const float* __restrict__ nrm,
                                                      const int* __restrict__ idx24, int* __restrict__ idxout)
{
    const int t = threadIdx.x, w = t >> 6, L = t & 63;
    const int p = blockIdx.x*4 + w;
    const int bbase = p & ~(N_-1);
    const float MX = 3.4e38f;
    float dv = MX; int di = 0x7fffffff;
    if (L < KS_) {
        const int ci = idx24[(size_t)p*KS_ + L];
        const float4* qr = (const float4*)(x1 + (size_t)p*64);
        const float4* cr = (const float4*)(x1 + (size_t)(bbase + ci)*64);
        float dot = 0.f;
        #pragma unroll
        for (int i = 0; i < 16; ++i) {
            float4 a = qr[i], bx = cr[i];
            dot += a.x*bx.x + a.y*bx.y + a.z*bx.z + a.w*bx.w;
        }
        dv = nrm[bbase + ci] - 2.f*dot;
        di = ci;
    }
    int myfin = 0;
    for (int r = 0; r < K_; ++r) {
        float bv = dv; int bg = di;
        #pragma unroll
        for (int off = 32; off; off >>= 1) {
            float ov = __shfl_xor(bv, off);
            int   og = __shfl_xor(bg, off);
            bool tk = (ov < bv) || (ov == bv && og < bg);
            bv = tk ? ov : bv; bg = tk ? og : bg;
        }
        if (L == r) myfin = bg;
        if (di == bg) dv = MX;
    }
    if (L < K_) idxout[(size_t)p*K_ + L] = myfin;
}

// ---------------------------------------------------------------- P/Q precompute
__global__ __launch_bounds__(256) void pq1_kernel(const float* __restrict__ x, const float* __restrict__ W,
                                                  const float* __restrict__ b1,
                                                  float* __restrict__ P, float* __restrict__ Q)
{
    __shared__ float wd[256], wb[256];
    const int t = threadIdx.x;
    wd[t] = W[t] - W[256 + t];
    wb[t] = W[256 + t];
    __syncthreads();
    const int p = blockIdx.x*4 + (t >> 6), c = t & 63;
    const float4 xv = ((const float4*)x)[p];
    float Pv = b1[c] + xv.x*wd[c] + xv.y*wd[64+c] + xv.z*wd[128+c] + xv.w*wd[192+c];
    float Qv =         xv.x*wb[c] + xv.y*wb[64+c] + xv.z*wb[128+c] + xv.w*wb[192+c];
    P[p*64 + c] = Pv;
    Q[p*64 + c] = Qv;
}

__global__ __launch_bounds__(256) void pq2_kernel(const float* __restrict__ x1, const float* __restrict__ W,
                                                  const float* __restrict__ b1,
                                                  float* __restrict__ P, float* __restrict__ Q)
{
    __shared__ float wd[64*128], wb[64*128];
    const int t = threadIdx.x;
    for (int e = t; e < 8192; e += 256) {
        float wt = W[e], wbo = W[8192 + e];
        wd[e] = wt - wbo; wb[e] = wbo;
    }
    __syncthreads();
    const int pl = t >> 7, c = t & 127;
    const float b1v = b1[c];
    for (int p0 = blockIdx.x*2; p0 < BN_; p0 += gridDim.x*2) {
        const int p = p0 + pl;
        float Pv = b1v, Qv = 0.f;
        const float* xrow = x1 + p*64;
        #pragma unroll 8
        for (int k = 0; k < 64; ++k) {
            float xv = xrow[k];
            Pv += xv * wd[k*128 + c];
            Qv += xv * wb[k*128 + c];
        }
        P[p*128 + c] = Pv;
        Q[p*128 + c] = Qv;
    }
}

// ---------------------------------------------------------------- layer-1 BN stats
template<int HO>
__global__ __launch_bounds__(256) void stats_l1_kernel(const float* __restrict__ P, const float* __restrict__ Q,
                                                       const int* __restrict__ idx, float* __restrict__ stOut)
{
    constexpr int G = 256/HO;
    __shared__ float red[256], red2[256];
    const int t = threadIdx.x, c = t % HO, g = t / HO;
    float s = 0.f, s2 = 0.f;
    for (int p = blockIdx.x; p < BN_; p += gridDim.x) {
        const float Pv = P[p*HO + c];
        const int bbase = p & ~(N_-1);
        for (int j = g; j < K_; j += G) {
            int m = idx[p*K_ + j];
            float z = Pv + Q[(bbase + m)*HO + c];
            s += z; s2 += z*z;
        }
    }
    red[t] = s; red2[t] = s2;
    __syncthreads();
    if (t < HO) {
        float a = red[t], a2 = red2[t];
        #pragma unroll
        for (int q = 1; q < G; ++q) { a += red[q*HO + t]; a2 += red2[q*HO + t]; }
        atomicAdd(&stOut[t], a);
        atomicAdd(&stOut[HO + t], a2);
    }
}

// ---------------------------------------------------------------- EdgeConv layer-2, exact fp32 (conv1:
// its output feeds kNN2, which is flip-sensitive to ~1e-4 feature perturbation)
template<int HO>
__global__ __launch_bounds__(256) void conv_l2_kernel(
    const float* __restrict__ P, const float* __restrict__ Q, const int* __restrict__ idx,
    const float* __restrict__ st1, const float* __restrict__ g1, const float* __restrict__ be1,
    const float* __restrict__ w2, const float* __restrict__ b2,
    float* __restrict__ zmax, float* __restrict__ zmin, float* __restrict__ stOut)
{
    __shared__ float w2s[HO*64];
    __shared__ float h1s[K_*HO];
    __shared__ float redA[256], redB[256];
    const int t = threadIdx.x;
    const int cy = blockIdx.y;
    for (int e = t; e < HO*64; e += 256) {
        int c = e >> 6, cl = e & 63;
        w2s[e] = w2[c*HO + cy*64 + cl];
    }
    const int cA = t % HO;
    const float ac = st1[3*HO + cA] * g1[cA];
    const float bc = be1[cA] - st1[2*HO + cA] * ac;
    const int c2l = t & 63, jh = t >> 6;
    const float b2v = b2[cy*64 + c2l];
    float ssum = 0.f, ssq = 0.f;
    for (int p = blockIdx.x; p < BN_; p += gridDim.x) {
        __syncthreads();
        const int bbase = p & ~(N_-1);
        const float Pv = P[p*HO + cA];
        for (int e = t; e < K_*HO; e += 256) {
            int j = e / HO;
            int m = idx[p*K_ + j];
            float z = Pv + Q[(bbase + m)*HO + cA];
            h1s[e] = fmaxf(z*ac + bc, 0.f);
        }
        __syncthreads();
        float acc[5];
        #pragma unroll
        for (int q = 0; q < 5; ++q) acc[q] = b2v;
        for (int c = 0; c < HO; ++c) {
            float wv = w2s[c*64 + c2l];
            #pragma unroll
            for (int q = 0; q < 5; ++q)
                acc[q] += h1s[(jh + q*4)*HO + c] * wv;
        }
        float mx = acc[0], mn = acc[0];
        #pragma unroll
        for (int q = 0; q < 5; ++q) {
            mx = fmaxf(mx, acc[q]); mn = fminf(mn, acc[q]);
            ssum += acc[q]; ssq += acc[q]*acc[q];
        }
        redA[t] = mx; redB[t] = mn;
        __syncthreads();
        if (t < 64) {
            float M = redA[t], Mn = redB[t];
            #pragma unroll
            for (int g = 1; g < 4; ++g) { M = fmaxf(M, redA[g*64 + t]); Mn = fminf(Mn, redB[g*64 + t]); }
            zmax[p*HO + cy*64 + t] = M;
            zmin[p*HO + cy*64 + t] = Mn;
        }
    }
    __syncthreads();
    redA[t] = ssum; redB[t] = ssq;
    __syncthreads();
    if (t < 64) {
        float s = redA[t], s2 = redB[t];
        #pragma unroll
        for (int g = 1; g < 4; ++g) { s += redA[g*64 + t]; s2 += redB[g*64 + t]; }
        atomicAdd(&stOut[cy*64 + t], s);
        atomicAdd(&stOut[HO + cy*64 + t], s2);
    }
}

// ---------------------------------------------------------------- W2^T split-bf16 prep
__global__ __launch_bounds__(256) void prep_w2t_kernel(const float* __restrict__ W,
                                                       unsigned short* __restrict__ wh,
                                                       unsigned short* __restrict__ wl, int HO)
{
    const int e = blockIdx.x*256 + threadIdx.x;   // e = k*HO + c
    const int k = e / HO, c = e % HO;
    const float v = W[e];
    unsigned short h = f2bf(v);
    float hf = __uint_as_float((unsigned)h << 16);
    wh[c*HO + k] = h;
    wl[c*HO + k] = f2bf(v - hf);
}

// ---------------------------------------------------------------- EdgeConv layer-2 via MFMA (split-bf16)
// conv2 only: output feeds the classifier (value-continuous), bf16-split safe.
template<int HO>
__global__ __launch_bounds__(256) void conv_l2_mfma_kernel(
    const float* __restrict__ P, const float* __restrict__ Q, const int* __restrict__ idx,
    const float* __restrict__ st1, const float* __restrict__ g1, const float* __restrict__ be1,
    const unsigned short* __restrict__ w2h, const unsigned short* __restrict__ w2l,
    const float* __restrict__ b2,
    float* __restrict__ zmax, float* __restrict__ zmin, float* __restrict__ stOut)
{
    constexpr int HOP = HO + 8;
    constexpr int CDP = HO + 1;
    constexpr int CTW = HO / 64;
    constexpr int KSn = HO / 32;
    constexpr int HSH = (HO == 128) ? 7 : 6;
    __shared__ __align__(16) short hs[2*80*HOP];
    __shared__ int sidx[80];
    float* cd = (float*)hs;

    const int t = threadIdx.x, w = t >> 6, L = t & 63;
    const int m16 = L & 15, q4 = L >> 4;

    const int kT = t & (HO - 1);
    const float ac = st1[3*HO + kT] * g1[kT];
    const float bc = be1[kT] - st1[2*HO + kT] * ac;

    bf16x8 Bh[CTW][KSn], Bl[CTW][KSn];
    #pragma unroll
    for (int ctl = 0; ctl < CTW; ++ctl)
        #pragma unroll
        for (int ks = 0; ks < KSn; ++ks) {
            const int c  = w*16*CTW + ctl*16 + m16;
            const int k0 = ks*32 + q4*8;
            Bh[ctl][ks] = *(const bf16x8*)(w2h + c*HO + k0);
            Bl[ctl][ks] = *(const bf16x8*)(w2l + c*HO + k0);
        }

    const float b2c = (t < HO) ? b2[t] : 0.f;
    float ssum = 0.f, ssq = 0.f;

    for (int p0 = blockIdx.x*4; p0 < BN_; p0 += gridDim.x*4) {
        const int bbase = p0 & ~(N_-1);
        __syncthreads();
        if (t < 80) sidx[t] = idx[p0*K_ + t];
        __syncthreads();
        for (int e = t; e < 80*HO; e += 256) {
            const int r  = e >> HSH;
            const int pl = (r*3277) >> 16;     // r/20 for r<80
            const int mI = sidx[r];
            float z = P[(size_t)(p0+pl)*HO + kT] + Q[(size_t)(bbase+mI)*HO + kT];
            float h = fmaxf(z*ac + bc, 0.f);
            unsigned short hh = f2bf(h);
            float hf = __uint_as_float((unsigned)hh << 16);
            unsigned short hl = f2bf(h - hf);
            hs[r*HOP + kT] = (short)hh;
            hs[80*HOP + r*HOP + kT] = (short)hl;
        }
        __syncthreads();
        f32x4 acc[5][CTW];
        #pragma unroll
        for (int rt = 0; rt < 5; ++rt)
            #pragma unroll
            for (int ctl = 0; ctl < CTW; ++ctl)
                acc[rt][ctl] = (f32x4){0.f, 0.f, 0.f, 0.f};
        #pragma unroll
        for (int rt = 0; rt < 5; ++rt)
            #pragma unroll
            for (int ks = 0; ks < KSn; ++ks) {
                const short* ap = hs + (rt*16 + m16)*HOP + ks*32 + q4*8;
                bf16x8 Ah = *(const bf16x8*)ap;
                bf16x8 Al = *(const bf16x8*)(ap + 80*HOP);
                #pragma unroll
                for (int ctl = 0; ctl < CTW; ++ctl) {
                    acc[rt][ctl] = __builtin_amdgcn_mfma_f32_16x16x32_bf16(Ah, Bh[ctl][ks], acc[rt][ctl], 0, 0, 0);
                    acc[rt][ctl] = __builtin_amdgcn_mfma_f32_16x16x32_bf16(Al, Bh[ctl][ks], acc[rt][ctl], 0, 0, 0);
                    acc[rt][ctl] = __builtin_amdgcn_mfma_f32_16x16x32_bf16(Ah, Bl[ctl][ks], acc[rt][ctl], 0, 0, 0);
                }
            }
        __syncthreads();
        #pragma unroll
        for (int rt = 0; rt < 5; ++rt)
            #pragma unroll
            for (int ctl = 0; ctl < CTW; ++ctl) {
                const int col = w*16*CTW + ctl*16 + m16;
                #pragma unroll
                for (int ri = 0; ri < 4; ++ri) {
                    const int row = rt*16 + q4*4 + ri;
                    cd[row*CDP + col] = acc[rt][ctl][ri];
                }
            }
        __syncthreads();
        if (t < HO) {
            #pragma unroll
            for (int pl = 0; pl < 4; ++pl) {
                float mx = -3.4e38f, mn = 3.4e38f;
                #pragma unroll
                for (int j = 0; j < K_; ++j) {
                    float v = cd[(pl*20 + j)*CDP + t] + b2c;
                    mx = fmaxf(mx, v); mn = fminf(mn, v);
                    ssum += v; ssq += v*v;
                }
                zmax[(size_t)(p0+pl)*HO + t] = mx;
                zmin[(size_t)(p0+pl)*HO + t] = mn;
            }
        }
    }
    if (t < HO) {
        atomicAdd(&stOut[t], ssum);
        atomicAdd(&stOut[HO + t], ssq);
    }
}

// max_j relu(BN(z)) = relu(BN(max_j z)) for gamma>=0, min for gamma<0
template<int HO>
__global__ __launch_bounds__(256) void conv_fin_kernel(
    const float* __restrict__ zmax, const float* __restrict__ zmin,
    const float* __restrict__ st2, const float* __restrict__ g2, const float* __restrict__ be2,
    float* __restrict__ out)
{
    int e = blockIdx.x*256 + threadIdx.x;
    int c = e & (HO-1);
    float g = g2[c];
    float a = st2[3*HO + c] * g;
    float sel = (g >= 0.f) ? zmax[e] : zmin[e];
    out[e] = fmaxf((sel - st2[2*HO + c]) * a + be2[c], 0.f);
}

// ---------------------------------------------------------------- classifier
__global__ __launch_bounds__(256) void cls1_kernel(
    const float* __restrict__ x1, const float* __restrict__ x2f,
    const float* __restrict__ W, const float* __restrict__ b1,
    float* __restrict__ z, float* __restrict__ stOut)
{
    __shared__ float ws[192*64];
    __shared__ float xr[4*192];
    __shared__ float red[256], red2[256];
    const int t = threadIdx.x, cy = blockIdx.y;
    for (int e = t; e < 192*64; e += 256) {
        int c = e >> 6, cl = e & 63;
        ws[e] = W[c*128 + cy*64 + cl];
    }
    const int pl = t >> 6, c2l = t & 63;
    const float b1v = b1[cy*64 + c2l];
    float ssum = 0.f, ssq = 0.f;
    for (int p0 = blockIdx.x*4; p0 < BN_; p0 += gridDim.x*4) {
        __syncthreads();
        for (int l = t; l < 4*192; l += 256) {
            int pp = l / 192, cc = l % 192;
            xr[l] = (cc < 64) ? x1[(p0+pp)*64 + cc] : x2f[(p0+pp)*128 + cc - 64];
        }
        __syncthreads();
        float acc = b1v;
        const float* xx = xr + pl*192;
        #pragma unroll 8
        for (int c = 0; c < 192; ++c) acc += xx[c] * ws[c*64 + c2l];
        z[(p0+pl)*128 + cy*64 + c2l] = acc;
        ssum += acc; ssq += acc*acc;
    }
    __syncthreads();
    red[t] = ssum; red2[t] = ssq;
    __syncthreads();
    if (t < 64) {
        float s = red[t], s2 = red2[t];
        #pragma unroll
        for (int g = 1; g < 4; ++g) { s += red[g*64 + t]; s2 += red2[g*64 + t]; }
        atomicAdd(&stOut[cy*64 + t], s);
        atomicAdd(&stOut[128 + cy*64 + t], s2);
    }
}

__global__ __launch_bounds__(256) void cls_fin_kernel(
    const float* __restrict__ z, const float* __restrict__ st,
    const float* __restrict__ g, const float* __restrict__ be,
    const float* __restrict__ w2, const float* __restrict__ b2,
    float* __restrict__ out)
{
    const int t = threadIdx.x, w = t >> 6, L = t & 63;
    const int p = blockIdx.x*4 + w;
    float s = 0.f;
    #pragma unroll
    for (int h = 0; h < 2; ++h) {
        int c = L + h*64;
        float v = (z[p*128 + c] - st[256 + c]) * st[384 + c] * g[c] + be[c];
        s += fmaxf(v, 0.f) * w2[c];
    }
    #pragma unroll
    for (int off = 32; off; off >>= 1) s += __shfl_xor(s, off);
    if (L == 0) out[p] = s + b2[0];
}

// ---------------------------------------------------------------- launch
extern "C" void kernel_launch(void* const* d_in, const int* in_sizes, int n_in,
                              void* d_out, int out_size, void* d_ws, size_t ws_size,
                              hipStream_t stream)
{
    const float* x      = (const float*)d_in[0];
    const float* c1_w1  = (const float*)d_in[1];
    const float* c1_b1  = (const float*)d_in[2];
    const float* c1_g1  = (const float*)d_in[3];
    const float* c1_be1 = (const float*)d_in[4];
    const float* c1_w2  = (const float*)d_in[5];
    const float* c1_b2  = (const float*)d_in[6];
    const float* c1_g2  = (const float*)d_in[7];
    const float* c1_be2 = (const float*)d_in[8];
    const float* c2_w1  = (const float*)d_in[9];
    const float* c2_b1  = (const float*)d_in[10];
    const float* c2_g1  = (const float*)d_in[11];
    const float* c2_be1 = (const float*)d_in[12];
    const float* c2_w2  = (const float*)d_in[13];
    const float* c2_b2  = (const float*)d_in[14];
    const float* c2_g2  = (const float*)d_in[15];
    const float* c2_be2 = (const float*)d_in[16];
    const float* cls_w1 = (const float*)d_in[17];
    const float* cls_b1 = (const float*)d_in[18];
    const float* cls_g1 = (const float*)d_in[19];
    const float* cls_be1= (const float*)d_in[20];
    const float* cls_w2 = (const float*)d_in[21];
    const float* cls_b2 = (const float*)d_in[22];
    (void)in_sizes; (void)n_in; (void)out_size; (void)ws_size;

    char* ws = (char*)d_ws;
    size_t off = 0;
    auto alloc = [&](size_t bytes) { char* p = ws + off; off += (bytes + 255) & ~255ull; return p; };
    float* A    = (float*)alloc((size_t)16<<20);   // P1 -> P2 -> zcls
    float* Bq   = (float*)alloc((size_t)16<<20);   // Q1 -> Q2
    float* zmax = (float*)alloc((size_t)16<<20);   // also hosts Xh/Xl between conv1 and conv2
    float* zmin = (float*)alloc((size_t)16<<20);
    float* x1b  = (float*)alloc((size_t)8<<20);
    float* x2b  = (float*)alloc((size_t)16<<20);   // also hosts idx24 during kNN2 phase
    int*   idx  = (int*)  alloc((size_t)BN_*K_*4); // idx1 -> idx2
    float* nrm  = (float*)alloc((size_t)BN_*4);
    float* st   = (float*)alloc((size_t)5*512*4);
    unsigned short* w2th = (unsigned short*)alloc((size_t)128*128*2);  // W2^T hi
    unsigned short* w2tl = (unsigned short*)alloc((size_t)128*128*2);  // W2^T lo
    float *st0 = st, *st1 = st+512, *st2 = st+1024, *st3 = st+1536, *st4 = st+2048;

    unsigned short* Xh = (unsigned short*)zmax;                       // 4 MB
    unsigned short* Xl = (unsigned short*)((char*)zmax + (4<<20));    // 4 MB
    int* idx24 = (int*)x2b;

    zero_kernel<<<1, 256, 0, stream>>>(st, 5*512);

    // ---- EdgeConv 1 (exact fp32 conv: x1b feeds flip-sensitive kNN2)
    knn4_kernel<<<dim3(N_/16, B_), 1024, 0, stream>>>(x, idx);
    pq1_kernel<<<BN_/4, 256, 0, stream>>>(x, c1_w1, c1_b1, A, Bq);
    stats_l1_kernel<64><<<2048, 256, 0, stream>>>(A, Bq, idx, st0);
    finalize_kernel<<<1, 128, 0, stream>>>(st0, 64, 1.f/655360.f);
    conv_l2_kernel<64><<<dim3(2048,1), 256, 0, stream>>>(A, Bq, idx, st0, c1_g1, c1_be1, c1_w2, c1_b2, zmax, zmin, st1);
    finalize_kernel<<<1, 128, 0, stream>>>(st1, 64, 1.f/655360.f);
    conv_fin_kernel<64><<<BN_*64/256, 256, 0, stream>>>(zmax, zmin, st1, c1_g2, c1_be2, x1b);

    // ---- EdgeConv 2 (MFMA conv: x2b only feeds classifier)
    prep64_kernel<<<BN_/4, 256, 0, stream>>>(x1b, Xh, Xl, nrm);
    knn64v4_kernel<<<dim3(N_/16, B_), 1024, 0, stream>>>(Xh, Xl, nrm, idx24);
    rescore_kernel<<<BN_/4, 256, 0, stream>>>(x1b, nrm, idx24, idx);
    pq2_kernel<<<1024, 256, 0, stream>>>(x1b, c2_w1, c2_b1, A, Bq);
    stats_l1_kernel<128><<<2048, 256, 0, stream>>>(A, Bq, idx, st2);
    finalize_kernel<<<1, 128, 0, stream>>>(st2, 128, 1.f/655360.f);
    prep_w2t_kernel<<<128*128/256, 256, 0, stream>>>(c2_w2, w2th, w2tl, 128);
    conv_l2_mfma_kernel<128><<<2048, 256, 0, stream>>>(A, Bq, idx, st2, c2_g1, c2_be1, w2th, w2tl, c2_b2, zmax, zmin, st3);
    finalize_kernel<<<1, 128, 0, stream>>>(st3, 128, 1.f/655360.f);
    conv_fin_kernel<128><<<BN_*128/256, 256, 0, stream>>>(zmax, zmin, st3, c2_g2, c2_be2, x2b);

    // ---- classifier
    cls1_kernel<<<dim3(512,2), 256, 0, stream>>>(x1b, x2b, cls_w1, cls_b1, A, st4);
    finalize_kernel<<<1, 128, 0, stream>>>(st4, 128, 1.f/32768.f);
    cls_fin_kernel<<<BN_/4, 256, 0, stream>>>(A, st4, cls_g1, cls_be1, cls_w2, cls_b2, (float*)d_out);
}